// Round 2
// baseline (2873.292 us; speedup 1.0000x reference)
//
#include <hip/hip_runtime.h>
#include <cstddef>
#include <cstdint>

#define DI __device__ __forceinline__

namespace {

constexpr int B_ = 16, T_ = 2048, H_ = 768, HH_ = 384, NSPAN_ = 24;
constexpr int NS_ = B_ * NSPAN_;          // 384 spans per type
constexpr int G4_ = 4 * HH_;              // 1536 gate width
constexpr int WMAX_ = 16;
constexpr int MAXTOK_ = NS_ * WMAX_;      // 6144 max covered tokens / rows

// ---------------- workspace layout (floats) ----------------
constexpr size_t XG_SZ  = (size_t)NS_ * WMAX_ * G4_;          // 9,437,184
constexpr size_t O_XG_A = 0;
constexpr size_t O_XG_O = O_XG_A + XG_SZ;
constexpr size_t O_QKV  = O_XG_O + XG_SZ;                     // 884,736  (gb overlays qkv+aot)
constexpr size_t O_AOT  = O_QKV + (size_t)NS_ * 3 * H_;       // 294,912
constexpr size_t O_RT   = O_AOT + (size_t)NS_ * H_;
constexpr size_t O_EA   = O_RT  + (size_t)NS_ * H_;
constexpr size_t O_EO   = O_EA  + (size_t)NS_ * H_;
constexpr size_t O_HB0  = O_EO  + (size_t)NS_ * H_;           // 2 types x NS x HH
constexpr size_t O_CST  = O_HB0 + 2 * (size_t)NS_ * HH_;
constexpr size_t O_HB1  = O_CST + 2 * (size_t)NS_ * HH_;
constexpr size_t F_TOTAL = O_HB1 + 2 * (size_t)NS_ * HH_;     // 21,823,488 floats
// ints after the float region
constexpr size_t I_STARTS  = 0;
constexpr size_t I_LENS    = I_STARTS + 2 * NS_;
constexpr size_t I_ORD     = I_LENS   + 2 * NS_;
constexpr size_t I_SLENS   = I_ORD    + 2 * NS_;
constexpr size_t I_XGLIST  = I_SLENS  + 2 * NS_;
constexpr size_t I_TOKLIST = I_XGLIST + 2 * MAXTOK_;
constexpr size_t I_CNT     = I_TOKLIST + 2 * MAXTOK_;         // [xg_a, xg_o, tok_a, tok_o]
// total ws bytes ~ 87.4 MB

DI float sigf(float x) { return 1.f / (1.f + __expf(-x)); }
DI float tanhfast(float x) {
  x = fminf(fmaxf(x, -15.f), 15.f);
  float e = __expf(2.f * x);
  return (e - 1.f) / (e + 1.f);
}

// ---------------- span metadata + active (span,t) list ----------------
__global__ void span_meta(const int* __restrict__ asp, const int* __restrict__ osp,
                          int* __restrict__ starts, int* __restrict__ lens,
                          int* __restrict__ xglist, int* __restrict__ cnt) {
  int i = blockIdx.x * blockDim.x + threadIdx.x;
  if (i >= 2 * NS_) return;
  int type = i / NS_, sp = i - type * NS_;
  const int* spans = type ? osp : asp;
  int s0 = spans[2 * sp], s1 = spans[2 * sp + 1];
  int st = min(max(s0, 0), T_ - 1);
  int en = min(max(s1, st + 1), T_);
  int ln = min(en - st, WMAX_);
  starts[i] = st;
  lens[i] = ln;
  for (int t = 0; t < ln; ++t) {
    int pos = atomicAdd(&cnt[type], 1);
    if (pos < MAXTOK_) xglist[type * MAXTOK_ + pos] = (sp << 4) | t;
  }
}

// counting sort of spans by len (desc) so recurrence blocks can early-exit
__global__ void sort_spans(const int* __restrict__ lens, int* __restrict__ ord,
                           int* __restrict__ slens) {
  int type = blockIdx.x;
  __shared__ int ls[NS_];
  __shared__ int os[NS_];
  __shared__ int hist[WMAX_], off[WMAX_];
  int tid = threadIdx.x;
  if (tid < WMAX_) hist[tid] = 0;
  __syncthreads();
  int myl = 1;
  if (tid < NS_) {
    myl = lens[type * NS_ + tid];
    ls[tid] = myl;
    atomicAdd(&hist[WMAX_ - myl], 1);   // bucket 0 = len 16 ... bucket 15 = len 1
  }
  __syncthreads();
  if (tid == 0) { int a = 0; for (int b = 0; b < WMAX_; ++b) { off[b] = a; a += hist[b]; } }
  __syncthreads();
  if (tid < NS_) { int pos = atomicAdd(&off[WMAX_ - myl], 1); os[pos] = tid; }
  __syncthreads();
  if (tid < NS_) { int sp = os[tid]; ord[type * NS_ + tid] = sp; slens[type * NS_ + tid] = ls[sp]; }
}

// covered-token list per type: (b*T + t) | (span_local << 20). Same-type spans never overlap.
__global__ void cov_build(const int* __restrict__ asp, const int* __restrict__ osp,
                          int* __restrict__ toklist, int* __restrict__ cnt2) {
  int i = blockIdx.x * blockDim.x + threadIdx.x;
  if (i >= 2 * NS_) return;
  int type = i / NS_, sp = i - type * NS_;
  const int* spans = type ? osp : asp;
  int b = sp / NSPAN_, s = sp - b * NSPAN_;
  int s0 = spans[2 * sp];
  int s1 = min(spans[2 * sp + 1], T_);
  int lo = max(s0, 0), hi = min(s1, s0 + WMAX_);
  for (int tt = lo; tt < hi; ++tt) {
    int pos = atomicAdd(&cnt2[type], 1);
    if (pos < MAXTOK_) toklist[type * MAXTOK_ + pos] = (b * T_ + tt) | (s << 20);
  }
}

// ---------------- generic fp32 tiled GEMM (64x64x16, 256 thr, 4x4/thread) ----------------
enum { M_XG = 0, M_XGB = 1, M_QKV = 2, M_OUTP = 3, M_AP1 = 4, M_AP2 = 5 };

struct GP {
  const float* A;      // primary A source
  const float* A2;     // kv source (QKV) / rep base e (AP1)
  const float* W;
  const float* bias;
  const float* resid;  // OUTP
  float* C;
  const int* list;     // row list (XG, AP1, AP2)
  const int* cnt;      // device row count
  const int* starts;   // XG, XGB
  const int* lens;     // XGB
  int K;
  int ldw;
  int lda;
};

template <int MODE>
__global__ __launch_bounds__(256) void gemm_k(GP p) {
  __shared__ float As[16][64];
  __shared__ float Ws[16][64];
  const int tid = threadIdx.x;
  const int m0 = blockIdx.x * 64;
  const int n0 = blockIdx.y * 64;
  int rows = 1 << 30;
  if constexpr (MODE == M_XG || MODE == M_AP1 || MODE == M_AP2) rows = min(*p.cnt, MAXTOK_);
  if (m0 >= rows) return;

  const int lrow = tid >> 2, kq = tid & 3;   // loader mapping
  const int lr = m0 + lrow;
  const bool aok = lr < rows;
  const float* aptr = nullptr;
  const float* aptr2 = nullptr;
  if (aok) {
    if constexpr (MODE == M_XG) {
      int e = p.list[lr]; int sp = e >> 4, tt = e & 15;
      int srow = min(max(p.starts[sp] + tt, 0), T_ - 1);
      aptr = p.A + ((size_t)((sp / NSPAN_) * T_ + srow)) * H_;
    } else if constexpr (MODE == M_XGB) {
      int sp = lr;
      int srow = min(max(p.starts[sp] + p.lens[sp] - 1, 0), T_ - 1);
      aptr = p.A + ((size_t)((sp / NSPAN_) * T_ + srow)) * H_;
    } else if constexpr (MODE == M_QKV) {
      aptr = ((n0 < H_) ? p.A : p.A2) + (size_t)lr * H_;
    } else if constexpr (MODE == M_AP1) {
      int e = p.list[lr]; int bt = e & 0xFFFFF; int s = e >> 20;
      aptr  = p.A + (size_t)bt * H_;                                   // current token value
      aptr2 = p.A2 + ((size_t)((bt >> 11) * NSPAN_ + s)) * H_;         // span rep (T_=2048=2^11)
    } else {
      aptr = p.A + (size_t)lr * p.lda;
    }
  }

  const int tcol = tid & 15, trow = tid >> 4;
  float acc[4][4] = {};
  for (int k0 = 0; k0 < p.K; k0 += 16) {
    float4 a4 = make_float4(0.f, 0.f, 0.f, 0.f);
    if (aok) {
      int kg = k0 + kq * 4;
      const float* sp_;
      if constexpr (MODE == M_AP1) sp_ = (kg < H_) ? (aptr + kg) : (aptr2 + (kg - H_));
      else sp_ = aptr + kg;
      a4 = *(const float4*)sp_;
    }
    As[kq * 4 + 0][lrow] = a4.x; As[kq * 4 + 1][lrow] = a4.y;
    As[kq * 4 + 2][lrow] = a4.z; As[kq * 4 + 3][lrow] = a4.w;
    if constexpr (MODE <= M_OUTP) {   // NT: W[n][k]
      float4 w4 = *(const float4*)(p.W + (size_t)(n0 + lrow) * p.ldw + k0 + kq * 4);
      Ws[kq * 4 + 0][lrow] = w4.x; Ws[kq * 4 + 1][lrow] = w4.y;
      Ws[kq * 4 + 2][lrow] = w4.z; Ws[kq * 4 + 3][lrow] = w4.w;
    } else {                          // NN: W[k][n]
      int kk = tid >> 4, cq = tid & 15;
      float4 w4 = *(const float4*)(p.W + (size_t)(k0 + kk) * p.ldw + n0 + cq * 4);
      *(float4*)&Ws[kk][cq * 4] = w4;
    }
    __syncthreads();
#pragma unroll
    for (int kk = 0; kk < 16; ++kk) {
      float ar[4] = {As[kk][trow], As[kk][trow + 16], As[kk][trow + 32], As[kk][trow + 48]};
      float wc[4] = {Ws[kk][tcol], Ws[kk][tcol + 16], Ws[kk][tcol + 32], Ws[kk][tcol + 48]};
#pragma unroll
      for (int i = 0; i < 4; ++i)
#pragma unroll
        for (int j = 0; j < 4; ++j) acc[i][j] = fmaf(ar[i], wc[j], acc[i][j]);
    }
    __syncthreads();
  }

#pragma unroll
  for (int i = 0; i < 4; ++i) {
    int row = m0 + trow + 16 * i;
    if (row >= rows) continue;
    if constexpr (MODE == M_XG) {
      int e = p.list[row]; int sp = e >> 4, tt = e & 15;
      float* cr = p.C + ((size_t)(sp * 16 + tt)) * G4_;
#pragma unroll
      for (int j = 0; j < 4; ++j) { int col = n0 + tcol + 16 * j; cr[col] = acc[i][j] + p.bias[col]; }
    } else if constexpr (MODE == M_XGB) {
      float* cr = p.C + (size_t)row * G4_;
#pragma unroll
      for (int j = 0; j < 4; ++j) { int col = n0 + tcol + 16 * j; cr[col] = acc[i][j] + p.bias[col]; }
    } else if constexpr (MODE == M_QKV) {
      float* cr = p.C + (size_t)row * (3 * H_);
#pragma unroll
      for (int j = 0; j < 4; ++j) { int col = n0 + tcol + 16 * j; cr[col] = acc[i][j] + p.bias[col]; }
    } else if constexpr (MODE == M_OUTP) {
      float* cr = p.C + (size_t)row * H_;
#pragma unroll
      for (int j = 0; j < 4; ++j) {
        int col = n0 + tcol + 16 * j;
        cr[col] = acc[i][j] + p.bias[col] + p.resid[(size_t)row * H_ + col];
      }
    } else if constexpr (MODE == M_AP1) {
      float* cr = p.C + (size_t)row * H_;
#pragma unroll
      for (int j = 0; j < 4; ++j) {
        int col = n0 + tcol + 16 * j;
        cr[col] = fmaxf(acc[i][j] + p.bias[col], 0.f);
      }
    } else {  // M_AP2: scatter to output token row
      int e = p.list[row]; int bt = e & 0xFFFFF;
      float* cr = p.C + (size_t)bt * H_;
#pragma unroll
      for (int j = 0; j < 4; ++j) { int col = n0 + tcol + 16 * j; cr[col] = acc[i][j] + p.bias[col]; }
    }
  }
}

// ---------------- backward (single-step) LSTM activation ----------------
__global__ void bwd_act(const float* __restrict__ gb, float* __restrict__ ea,
                        float* __restrict__ eo) {
  int idx = blockIdx.x * 256 + threadIdx.x;
  if (idx >= 2 * NS_ * HH_) return;
  int type = idx / (NS_ * HH_);
  int rem = idx - type * NS_ * HH_;
  int sp = rem / HH_, j = rem - sp * HH_;
  const float* g = gb + ((size_t)type * NS_ + sp) * G4_;
  float cb = sigf(g[j]) * tanhfast(g[2 * HH_ + j]);
  float hb = sigf(g[3 * HH_ + j]) * tanhfast(cb);
  (type ? eo : ea)[(size_t)sp * H_ + HH_ + j] = hb;
}

// ---------------- one LSTM recurrence step (both types) ----------------
struct RP {
  const float* hprev;            // [2][NS][HH] double-buffer (read side)
  float* hout_a; float* hout_o;  // write side (hbuf or ea/eo at t==15)
  int hstride;
  float* cst;                    // [2][NS][HH]
  const float* xg_a; const float* xg_o;
  const float* whh_a; const float* whh_o;
  const int* ord; const int* slens; const int* lens;
  int t;
};

__global__ __launch_bounds__(256) void lstm_step(RP p) {
  int bx = blockIdx.x;                 // 0..47  (24 span-blocks x 2 types)
  int type = bx / 24;
  int sb = (bx - type * 24) * 16;      // sorted-span base
  int jb = blockIdx.y * 64;            // hh base
  int tid = threadIdx.x;
  const int* ordt = p.ord + type * NS_;
  const int* lenst = p.lens + type * NS_;
  float* hout = type ? p.hout_o : p.hout_a;
  const float* hprev = p.hprev + (size_t)type * NS_ * HH_;
  float* cstt = p.cst + (size_t)type * NS_ * HH_;
  const float* xg = type ? p.xg_o : p.xg_a;
  const float* whh = type ? p.whh_o : p.whh_a;

  int maxlen = p.slens[type * NS_ + sb];    // sorted desc -> max in block
  if (maxlen <= p.t) {                      // all spans done: just carry state
    for (int e = tid; e < 16 * 64; e += 256) {
      int s = e >> 6, c = e & 63;
      int sp = ordt[sb + s];
      hout[(size_t)sp * p.hstride + jb + c] = hprev[(size_t)sp * HH_ + jb + c];
    }
    return;
  }

  __shared__ int spid[16], splen[16];
  __shared__ float hsm[16][32];
  __shared__ float wsm[256][33];
  if (tid < 16) { int sp = ordt[sb + tid]; spid[tid] = sp; splen[tid] = lenst[sp]; }
  __syncthreads();

  int j = tid & 63;
  int sg = tid >> 6;
  float acc[4][4] = {};
  for (int kc = 0; kc < HH_; kc += 32) {
#pragma unroll
    for (int u = 0; u < 2; ++u) {
      int idx = tid * 2 + u;
      int s = idx >> 5, k = idx & 31;
      hsm[s][k] = hprev[(size_t)spid[s] * HH_ + kc + k];
    }
#pragma unroll
    for (int rep = 0; rep < 8; ++rep) {
      int row = (tid >> 3) + rep * 32;       // 0..255 = gate*64 + jj
      int fq = tid & 7;
      int grow = (row >> 6) * HH_ + jb + (row & 63);
      float4 w4 = *(const float4*)(whh + (size_t)grow * HH_ + kc + fq * 4);
      wsm[row][fq * 4 + 0] = w4.x; wsm[row][fq * 4 + 1] = w4.y;
      wsm[row][fq * 4 + 2] = w4.z; wsm[row][fq * 4 + 3] = w4.w;
    }
    __syncthreads();
#pragma unroll
    for (int k = 0; k < 32; ++k) {
      float hv[4], wv[4];
#pragma unroll
      for (int i = 0; i < 4; ++i) hv[i] = hsm[sg * 4 + i][k];
#pragma unroll
      for (int q = 0; q < 4; ++q) wv[q] = wsm[q * 64 + j][k];
#pragma unroll
      for (int i = 0; i < 4; ++i)
#pragma unroll
        for (int q = 0; q < 4; ++q) acc[i][q] = fmaf(hv[i], wv[q], acc[i][q]);
    }
    __syncthreads();
  }

  int col = jb + j;
#pragma unroll
  for (int i2 = 0; i2 < 4; ++i2) {
    int sl = sg * 4 + i2;
    int sp = spid[sl];
    int ln = splen[sl];
    const float* xr = xg + ((size_t)(sp * 16 + p.t)) * G4_;
    float gi = acc[i2][0] + xr[col];
    float gf = acc[i2][1] + xr[HH_ + col];
    float gg = acc[i2][2] + xr[2 * HH_ + col];
    float go = acc[i2][3] + xr[3 * HH_ + col];
    float hold = hprev[(size_t)sp * HH_ + col];
    float co = cstt[(size_t)sp * HH_ + col];
    float cn = sigf(gf) * co + sigf(gi) * tanhfast(gg);
    float hn = sigf(go) * tanhfast(cn);
    bool act = (p.t < ln);
    hout[(size_t)sp * p.hstride + col] = act ? hn : hold;
    if (act) cstt[(size_t)sp * HH_ + col] = cn;
  }
}

// ---------------- attention core: one (b, head) per block ----------------
__global__ __launch_bounds__(256) void attn_core(const float* __restrict__ qkv,
                                                 float* __restrict__ aot) {
  int b = blockIdx.x >> 3, h = blockIdx.x & 7;
  __shared__ float qs[24][97], ks[24][97], vs[24][97];
  __shared__ float sc[24][25];
  __shared__ float sinv[24];
  int tid = threadIdx.x;
  for (int idx = tid; idx < 24 * 96; idx += 256) {
    int s = idx / 96, d = idx - s * 96;
    size_t rb = ((size_t)(b * 24 + s)) * (3 * H_) + h * 96 + d;
    qs[s][d] = qkv[rb];
    ks[s][d] = qkv[rb + H_];
    vs[s][d] = qkv[rb + 2 * H_];
  }
  __syncthreads();
  for (int pp = tid; pp < 576; pp += 256) {
    int qi = pp / 24, ki = pp - qi * 24;
    float a = 0.f;
    for (int d = 0; d < 96; ++d) a = fmaf(qs[qi][d], ks[ki][d], a);
    sc[qi][ki] = a * 0.10206207261596577f;   // 1/sqrt(96)
  }
  __syncthreads();
  if (tid < 24) {
    float m = -1e30f;
    for (int k2 = 0; k2 < 24; ++k2) m = fmaxf(m, sc[tid][k2]);
    float ssum = 0.f;
    for (int k2 = 0; k2 < 24; ++k2) { float e = __expf(sc[tid][k2] - m); sc[tid][k2] = e; ssum += e; }
    sinv[tid] = 1.f / ssum;
  }
  __syncthreads();
  for (int idx = tid; idx < 24 * 96; idx += 256) {
    int s = idx / 96, d = idx - s * 96;
    float a = 0.f;
    for (int k2 = 0; k2 < 24; ++k2) a = fmaf(sc[s][k2], vs[k2][d], a);
    aot[((size_t)(b * 24 + s)) * H_ + h * 96 + d] = a * sinv[s];
  }
}

// ---------------- layernorm over H per row ----------------
__global__ __launch_bounds__(256) void ln_k(const float* __restrict__ x,
                                            const float* __restrict__ g,
                                            const float* __restrict__ bb,
                                            float* __restrict__ dst) {
  int row = blockIdx.x;
  const float* xr = x + (size_t)row * H_;
  float vals[3];
  float s1 = 0.f, s2 = 0.f;
#pragma unroll
  for (int u = 0; u < 3; ++u) {
    float v = xr[threadIdx.x + 256 * u];
    vals[u] = v; s1 += v; s2 += v * v;
  }
  for (int o = 32; o > 0; o >>= 1) { s1 += __shfl_down(s1, o, 64); s2 += __shfl_down(s2, o, 64); }
  __shared__ float r1[4], r2[4];
  __shared__ float mu_s, rs_s;
  int w = threadIdx.x >> 6, lane = threadIdx.x & 63;
  if (lane == 0) { r1[w] = s1; r2[w] = s2; }
  __syncthreads();
  if (threadIdx.x == 0) {
    float t1 = r1[0] + r1[1] + r1[2] + r1[3];
    float t2 = r2[0] + r2[1] + r2[2] + r2[3];
    float mu = t1 / (float)H_;
    float var = t2 / (float)H_ - mu * mu;
    mu_s = mu; rs_s = rsqrtf(var + 1e-5f);
  }
  __syncthreads();
#pragma unroll
  for (int u = 0; u < 3; ++u) {
    int c = threadIdx.x + 256 * u;
    dst[(size_t)row * H_ + c] = (vals[u] - mu_s) * rs_s * g[c] + bb[c];
  }
}

}  // namespace

extern "C" void kernel_launch(void* const* d_in, const int* in_sizes, int n_in,
                              void* d_out, int out_size, void* d_ws, size_t ws_size,
                              hipStream_t stream) {
  (void)in_sizes; (void)n_in; (void)out_size; (void)ws_size;
  const float* hs = (const float*)d_in[0];
  const int* asp = (const int*)d_in[1];
  const int* osp = (const int*)d_in[2];
  const float* a_wih_f = (const float*)d_in[3];
  const float* a_whh_f = (const float*)d_in[4];
  const float* a_b_f   = (const float*)d_in[5];
  const float* a_wih_b = (const float*)d_in[6];
  const float* a_b_b   = (const float*)d_in[8];
  const float* o_wih_f = (const float*)d_in[9];
  const float* o_whh_f = (const float*)d_in[10];
  const float* o_b_f   = (const float*)d_in[11];
  const float* o_wih_b = (const float*)d_in[12];
  const float* o_b_b   = (const float*)d_in[14];
  const float* ao_in_w  = (const float*)d_in[15];
  const float* ao_in_b  = (const float*)d_in[16];
  const float* ao_out_w = (const float*)d_in[17];
  const float* ao_out_b = (const float*)d_in[18];
  const float* oa_in_w  = (const float*)d_in[19];
  const float* oa_in_b  = (const float*)d_in[20];
  const float* oa_out_w = (const float*)d_in[21];
  const float* oa_out_b = (const float*)d_in[22];
  const float* ln_a_g = (const float*)d_in[23];
  const float* ln_a_b = (const float*)d_in[24];
  const float* ln_o_g = (const float*)d_in[25];
  const float* ln_o_b = (const float*)d_in[26];
  const float* p_w1 = (const float*)d_in[27];
  const float* p_b1 = (const float*)d_in[28];
  const float* p_w2 = (const float*)d_in[29];
  const float* p_b2 = (const float*)d_in[30];
  float* out = (float*)d_out;

  float* F = (float*)d_ws;
  int* I = (int*)((char*)d_ws + F_TOTAL * sizeof(float));
  float* xg_a = F + O_XG_A;
  float* xg_o = F + O_XG_O;
  float* qkv  = F + O_QKV;
  float* aot  = F + O_AOT;
  float* rt   = F + O_RT;
  float* ea   = F + O_EA;
  float* eo   = F + O_EO;
  float* hb0  = F + O_HB0;
  float* cst  = F + O_CST;
  float* hb1  = F + O_HB1;
  float* gb   = F + O_QKV;    // overlay (dead before attention)
  float* h1   = F + O_XG_A;   // overlay (xg dead after recurrence)
  int* starts = I + I_STARTS;
  int* lens   = I + I_LENS;
  int* ord    = I + I_ORD;
  int* slens  = I + I_SLENS;
  int* xglist = I + I_XGLIST;
  int* toklist = I + I_TOKLIST;
  int* cnt    = I + I_CNT;

  // passthrough tokens: out starts as hidden_states
  hipMemcpyAsync(out, hs, (size_t)B_ * T_ * H_ * sizeof(float),
                 hipMemcpyDeviceToDevice, stream);
  hipMemsetAsync(cnt, 0, 4 * sizeof(int), stream);
  // zero h double-buffer[0] and c state (contiguous region)
  hipMemsetAsync(hb0, 0, 4 * (size_t)NS_ * HH_ * sizeof(float), stream);

  span_meta<<<3, 256, 0, stream>>>(asp, osp, starts, lens, xglist, cnt);
  sort_spans<<<2, 384, 0, stream>>>(lens, ord, slens);
  cov_build<<<3, 256, 0, stream>>>(asp, osp, toklist, cnt + 2);

  // LSTM input projections (only active (span,t) rows)
  {
    GP g{}; g.A = hs; g.W = a_wih_f; g.bias = a_b_f; g.C = xg_a;
    g.list = xglist; g.cnt = cnt; g.starts = starts; g.K = H_; g.ldw = H_;
    gemm_k<M_XG><<<dim3(96, 24), 256, 0, stream>>>(g);
  }
  {
    GP g{}; g.A = hs; g.W = o_wih_f; g.bias = o_b_f; g.C = xg_o;
    g.list = xglist + MAXTOK_; g.cnt = cnt + 1; g.starts = starts + NS_; g.K = H_; g.ldw = H_;
    gemm_k<M_XG><<<dim3(96, 24), 256, 0, stream>>>(g);
  }
  {
    GP g{}; g.A = hs; g.W = a_wih_b; g.bias = a_b_b; g.C = gb;
    g.starts = starts; g.lens = lens; g.K = H_; g.ldw = H_;
    gemm_k<M_XGB><<<dim3(6, 24), 256, 0, stream>>>(g);
  }
  {
    GP g{}; g.A = hs; g.W = o_wih_b; g.bias = o_b_b; g.C = gb + (size_t)NS_ * G4_;
    g.starts = starts + NS_; g.lens = lens + NS_; g.K = H_; g.ldw = H_;
    gemm_k<M_XGB><<<dim3(6, 24), 256, 0, stream>>>(g);
  }
  bwd_act<<<(2 * NS_ * HH_ + 255) / 256, 256, 0, stream>>>(gb, ea, eo);

  // 16-step recurrence, double-buffered h; final step writes straight into ea/eo
  for (int t = 0; t < 16; ++t) {
    RP rp{};
    rp.hprev = (t & 1) ? hb1 : hb0;
    float* hn = (t & 1) ? hb0 : hb1;
    if (t == 15) { rp.hout_a = ea; rp.hout_o = eo; rp.hstride = H_; }
    else { rp.hout_a = hn; rp.hout_o = hn + (size_t)NS_ * HH_; rp.hstride = HH_; }
    rp.cst = cst; rp.xg_a = xg_a; rp.xg_o = xg_o;
    rp.whh_a = a_whh_f; rp.whh_o = o_whh_f;
    rp.ord = ord; rp.slens = slens; rp.lens = lens; rp.t = t;
    lstm_step<<<dim3(48, 6), 256, 0, stream>>>(rp);
  }

  // L=2 layers of cross attention (ea first, then eo with updated ea)
  for (int l = 0; l < 2; ++l) {
    for (int dir = 0; dir < 2; ++dir) {
      float* q  = dir ? eo : ea;
      float* kv = dir ? ea : eo;
      const float* inw = (dir ? oa_in_w : ao_in_w) + (size_t)l * 3 * H_ * H_;
      const float* inb = (dir ? oa_in_b : ao_in_b) + (size_t)l * 3 * H_;
      const float* ow  = (dir ? oa_out_w : ao_out_w) + (size_t)l * H_ * H_;
      const float* ob  = (dir ? oa_out_b : ao_out_b) + (size_t)l * H_;
      const float* lg  = (dir ? ln_o_g : ln_a_g) + (size_t)l * H_;
      const float* lb  = (dir ? ln_o_b : ln_a_b) + (size_t)l * H_;
      {
        GP g{}; g.A = q; g.A2 = kv; g.W = inw; g.bias = inb; g.C = qkv;
        g.K = H_; g.ldw = H_; g.lda = H_;
        gemm_k<M_QKV><<<dim3(6, 36), 256, 0, stream>>>(g);
      }
      attn_core<<<128, 256, 0, stream>>>(qkv, aot);
      {
        GP g{}; g.A = aot; g.W = ow; g.bias = ob; g.resid = q; g.C = rt;
        g.K = H_; g.ldw = H_; g.lda = H_;
        gemm_k<M_OUTP><<<dim3(6, 12), 256, 0, stream>>>(g);
      }
      ln_k<<<NS_, 256, 0, stream>>>(rt, lg, lb, q);
    }
  }

  // apply spans: aspect pass then opinion pass (opinion reads post-aspect tokens)
  for (int type = 0; type < 2; ++type) {
    {
      GP g{}; g.A = out; g.A2 = type ? eo : ea; g.W = p_w1; g.bias = p_b1; g.C = h1;
      g.list = toklist + (size_t)type * MAXTOK_; g.cnt = cnt + 2 + type;
      g.K = 2 * H_; g.ldw = H_;
      gemm_k<M_AP1><<<dim3(96, 12), 256, 0, stream>>>(g);
    }
    {
      GP g{}; g.A = h1; g.W = p_w2; g.bias = p_b2; g.C = out;
      g.list = toklist + (size_t)type * MAXTOK_; g.cnt = cnt + 2 + type;
      g.K = H_; g.ldw = H_; g.lda = H_;
      gemm_k<M_AP2><<<dim3(96, 12), 256, 0, stream>>>(g);
    }
  }
}

// Round 3
// 1519.117 us; speedup vs baseline: 1.8914x; 1.8914x over previous
//
#include <hip/hip_runtime.h>
#include <cstddef>
#include <cstdint>

#define DI __device__ __forceinline__

namespace {

typedef short short8 __attribute__((ext_vector_type(8)));
typedef float f32x4 __attribute__((ext_vector_type(4)));

constexpr int B_ = 16, T_ = 2048, H_ = 768, HH_ = 384, NSPAN_ = 24;
constexpr int NS_ = B_ * NSPAN_;          // 384 spans per type
constexpr int G4_ = 4 * HH_;              // 1536 gate width
constexpr int WMAX_ = 16;
constexpr int MAXTOK_ = NS_ * WMAX_;      // 6144 max gathered rows

// ---------------- workspace layout (bytes) ----------------
// bf16 weight arena (ushort element offsets within it)
constexpr size_t W_AWIF = 0;               // 1536x768
constexpr size_t W_OWIF = 1179648;
constexpr size_t W_AWIB = 2359296;
constexpr size_t W_OWIB = 3538944;
constexpr size_t W_AWHH = 4718592;         // 1536x384
constexpr size_t W_OWHH = 5308416;
constexpr size_t W_AOIN = 5898240;         // 2x2304x768
constexpr size_t W_OAIN = 9437184;
constexpr size_t W_AOOUT = 12976128;       // 2x768x768
constexpr size_t W_OAOUT = 14155776;
constexpr size_t W_PW1T = 15335424;        // 768x1536 (transposed)
constexpr size_t W_PW2T = 16515072;        // 768x768  (transposed)
constexpr size_t W_TOTEL = 17104896;

constexpr size_t WB_B   = 0;
constexpr size_t WB_SZ  = W_TOTEL * 2;                    // 34,209,792
constexpr size_t XGSZ_B = (size_t)NS_ * 16 * G4_ * 2;     // 18,874,368 (bf16)
constexpr size_t XGA_B  = WB_B + WB_SZ;
constexpr size_t XGO_B  = XGA_B + XGSZ_B;
constexpr size_t QKV_B  = XGO_B + XGSZ_B;                 // f32 NS x 2304
constexpr size_t AOT_B  = QKV_B + (size_t)NS_ * 2304 * 4;
constexpr size_t RT_B   = AOT_B + (size_t)NS_ * H_ * 4;
constexpr size_t EA_B   = RT_B + (size_t)NS_ * H_ * 4;
constexpr size_t EO_B   = EA_B + (size_t)NS_ * H_ * 4;
constexpr size_t HB_B   = EO_B + (size_t)NS_ * H_ * 4;    // h bufs bf16 [2][2][384][384]
constexpr size_t CST_B  = HB_B + 2ull * 2 * 384 * 384 * 2;
constexpr size_t INT_B  = CST_B + 2ull * 384 * 384 * 4;   // ~82.6 MB total
// ints (element offsets from INT_B)
constexpr size_t I_STARTS = 0;
constexpr size_t I_LENS   = I_STARTS + 2 * NS_;
constexpr size_t I_ORD    = I_LENS + 2 * NS_;
constexpr size_t I_SLENS  = I_ORD + 2 * NS_;
constexpr size_t I_XGLIST = I_SLENS + 2 * NS_;
constexpr size_t I_TOKLIST = I_XGLIST + 2 * MAXTOK_;
constexpr size_t I_CNT    = I_TOKLIST + 2 * MAXTOK_;

DI float sigf(float x) { return 1.f / (1.f + __expf(-x)); }
DI float tanhfast(float x) {
  x = fminf(fmaxf(x, -15.f), 15.f);
  float e = __expf(2.f * x);
  return (e - 1.f) / (e + 1.f);
}
DI unsigned short f2bf(float f) {
  unsigned u = __float_as_uint(f);
  return (unsigned short)((u + 0x7fffu + ((u >> 16) & 1u)) >> 16);
}
DI unsigned pk2(float lo, float hi) {
  return (unsigned)f2bf(lo) | ((unsigned)f2bf(hi) << 16);
}
DI float bf2f(unsigned short u) { return __uint_as_float(((unsigned)u) << 16); }

// ---------------- weight prep: f32 -> bf16 (+transpose for p_w1/p_w2) ----------------
struct PJ { const float* src; unsigned short* dst; int n; int R; int C; int tr; };
struct PREP { PJ j[12]; };

__global__ __launch_bounds__(256) void prep_w(PREP pp) {
  PJ job = pp.j[blockIdx.y];
  int stride = gridDim.x * blockDim.x;
  int g = blockIdx.x * blockDim.x + threadIdx.x;
  if (!job.tr) {
    int n4 = job.n >> 2;
    for (int i = g; i < n4; i += stride) {
      float4 v = ((const float4*)job.src)[i];
      ushort4 o;
      o.x = f2bf(v.x); o.y = f2bf(v.y); o.z = f2bf(v.z); o.w = f2bf(v.w);
      ((ushort4*)job.dst)[i] = o;
    }
  } else {
    for (int i = g; i < job.n; i += stride) {
      int r = i / job.C, c = i - r * job.C;
      job.dst[(size_t)c * job.R + r] = f2bf(job.src[i]);
    }
  }
}

// ---------------- span metadata + active (span,t) list ----------------
__global__ void span_meta(const int* __restrict__ asp, const int* __restrict__ osp,
                          int* __restrict__ starts, int* __restrict__ lens,
                          int* __restrict__ xglist, int* __restrict__ cnt) {
  int i = blockIdx.x * blockDim.x + threadIdx.x;
  if (i >= 2 * NS_) return;
  int type = i / NS_, sp = i - type * NS_;
  const int* spans = type ? osp : asp;
  int s0 = spans[2 * sp], s1 = spans[2 * sp + 1];
  int st = min(max(s0, 0), T_ - 1);
  int en = min(max(s1, st + 1), T_);
  int ln = min(en - st, WMAX_);
  starts[i] = st;
  lens[i] = ln;
  for (int t = 0; t < ln; ++t) {
    int pos = atomicAdd(&cnt[type], 1);
    if (pos < MAXTOK_) xglist[type * MAXTOK_ + pos] = (sp << 4) | t;
  }
}

__global__ void sort_spans(const int* __restrict__ lens, int* __restrict__ ord,
                           int* __restrict__ slens) {
  int type = blockIdx.x;
  __shared__ int ls[NS_];
  __shared__ int os[NS_];
  __shared__ int hist[WMAX_], off[WMAX_];
  int tid = threadIdx.x;
  if (tid < WMAX_) hist[tid] = 0;
  __syncthreads();
  int myl = 1;
  if (tid < NS_) {
    myl = lens[type * NS_ + tid];
    ls[tid] = myl;
    atomicAdd(&hist[WMAX_ - myl], 1);
  }
  __syncthreads();
  if (tid == 0) { int a = 0; for (int b = 0; b < WMAX_; ++b) { off[b] = a; a += hist[b]; } }
  __syncthreads();
  if (tid < NS_) { int pos = atomicAdd(&off[WMAX_ - myl], 1); os[pos] = tid; }
  __syncthreads();
  if (tid < NS_) { int sp = os[tid]; ord[type * NS_ + tid] = sp; slens[type * NS_ + tid] = ls[sp]; }
}

__global__ void cov_build(const int* __restrict__ asp, const int* __restrict__ osp,
                          int* __restrict__ toklist, int* __restrict__ cnt2) {
  int i = blockIdx.x * blockDim.x + threadIdx.x;
  if (i >= 2 * NS_) return;
  int type = i / NS_, sp = i - type * NS_;
  const int* spans = type ? osp : asp;
  int b = sp / NSPAN_, s = sp - b * NSPAN_;
  int s0 = spans[2 * sp];
  int s1 = min(spans[2 * sp + 1], T_);
  int lo = max(s0, 0), hi = min(s1, s0 + WMAX_);
  for (int tt = lo; tt < hi; ++tt) {
    int pos = atomicAdd(&cnt2[type], 1);
    if (pos < MAXTOK_) toklist[type * MAXTOK_ + pos] = (b * T_ + tt) | (s << 20);
  }
}

// ---------------- bf16 MFMA GEMM, 128x128x64 tile, 4 waves ----------------
enum { M_XG = 0, M_XGB = 1, M_QKV = 2, M_OUTP = 3, M_AP1 = 4, M_AP2 = 5 };

struct GP {
  const float* A;
  const float* A2;
  const unsigned short* Wb;   // bf16 W [N][K]
  const unsigned short* Ab;   // bf16 A (AP2)
  const float* bias;
  const float* resid;
  float* C;
  unsigned short* Cb;
  const int* list;
  const int* cnt;
  const int* starts;
  const int* lens;
  int K;
};

template <int MODE>
__global__ __launch_bounds__(256) void mgemm(GP p) {
  __shared__ __align__(16) unsigned short As[128 * 64];
  __shared__ __align__(16) unsigned short Bs[128 * 64];
  const int tid = threadIdx.x;
  const int m0 = blockIdx.x * 128, n0 = blockIdx.y * 128;
  int rows = NS_;
  if constexpr (MODE == M_XG || MODE == M_AP1 || MODE == M_AP2) rows = min(*p.cnt, MAXTOK_);
  if (m0 >= rows) return;

  // staging assignment: row = tid>>1, k-half (32 elems) = tid&1
  const int ar = tid >> 1, kh = tid & 1;
  const int lr = m0 + ar;
  const bool aok = lr < rows;
  const float* aptr = nullptr;
  const float* aptr2 = nullptr;
  const unsigned short* abptr = nullptr;
  if (aok) {
    if constexpr (MODE == M_XG) {
      int e = p.list[lr]; int sp = e >> 4, tt = e & 15;
      int srow = min(p.starts[sp] + tt, T_ - 1);
      aptr = p.A + ((size_t)((sp / NSPAN_) * T_ + srow)) * H_;
    } else if constexpr (MODE == M_XGB) {
      int sp = lr;
      int srow = min(max(p.starts[sp] + p.lens[sp] - 1, 0), T_ - 1);
      aptr = p.A + ((size_t)((sp / NSPAN_) * T_ + srow)) * H_;
    } else if constexpr (MODE == M_QKV) {
      aptr = ((n0 < H_) ? p.A : p.A2) + (size_t)lr * H_;
    } else if constexpr (MODE == M_OUTP) {
      aptr = p.A + (size_t)lr * H_;
    } else if constexpr (MODE == M_AP1) {
      int e = p.list[lr]; int bt = e & 0xFFFFF; int s = e >> 20;
      aptr = p.A + (size_t)bt * H_;
      aptr2 = p.A2 + ((size_t)((bt >> 11) * NSPAN_ + s)) * H_;
    } else {  // M_AP2
      abptr = p.Ab + (size_t)lr * H_;
    }
  }
  const unsigned short* brow = p.Wb + (size_t)(n0 + ar) * p.K;

  const int lane = tid & 63, wv = tid >> 6, wr = wv >> 1, wc = wv & 1;
  const int abase_r = wr * 64 + (lane & 15);
  const int bbase_r = wc * 64 + (lane & 15);
  const int kcol = lane >> 4;
  const int swz = (lane & 7) << 4;

  f32x4 acc[4][4];
#pragma unroll
  for (int mi = 0; mi < 4; ++mi)
#pragma unroll
    for (int ni = 0; ni < 4; ++ni) acc[mi][ni] = (f32x4){0.f, 0.f, 0.f, 0.f};

  for (int k0 = 0; k0 < p.K; k0 += 64) {
    // ---- stage A ----
    if constexpr (MODE == M_AP2) {
      if (aok) {
        const unsigned short* s = abptr + k0 + kh * 32;
#pragma unroll
        for (int c = 0; c < 4; ++c)
          *(uint4*)((char*)As + ar * 128 + ((((kh * 4 + c) * 16)) ^ ((ar & 7) << 4))) =
              *(const uint4*)(s + c * 8);
      }
    } else {
      if (aok) {
#pragma unroll
        for (int c = 0; c < 4; ++c) {
          int kg = k0 + kh * 32 + c * 8;
          const float* s;
          if constexpr (MODE == M_AP1) s = (kg < H_) ? (aptr + kg) : (aptr2 + (kg - H_));
          else s = aptr + kg;
          float4 u = *(const float4*)s;
          float4 v = *(const float4*)(s + 4);
          uint4 w;
          w.x = pk2(u.x, u.y); w.y = pk2(u.z, u.w);
          w.z = pk2(v.x, v.y); w.w = pk2(v.z, v.w);
          *(uint4*)((char*)As + ar * 128 + ((((kh * 4 + c) * 16)) ^ ((ar & 7) << 4))) = w;
        }
      }
    }
    // ---- stage B (bf16 weights, direct copy) ----
    {
      const unsigned short* s = brow + k0 + kh * 32;
#pragma unroll
      for (int c = 0; c < 4; ++c)
        *(uint4*)((char*)Bs + ar * 128 + ((((kh * 4 + c) * 16)) ^ ((ar & 7) << 4))) =
            *(const uint4*)(s + c * 8);
    }
    __syncthreads();
#pragma unroll
    for (int ks = 0; ks < 2; ++ks) {
      short8 af[4], bq[4];
#pragma unroll
      for (int i = 0; i < 4; ++i)
        af[i] = *(const short8*)((char*)As + (abase_r + i * 16) * 128 +
                                 (((ks * 4 + kcol) * 16) ^ swz));
#pragma unroll
      for (int i = 0; i < 4; ++i)
        bq[i] = *(const short8*)((char*)Bs + (bbase_r + i * 16) * 128 +
                                 (((ks * 4 + kcol) * 16) ^ swz));
#pragma unroll
      for (int mi = 0; mi < 4; ++mi)
#pragma unroll
        for (int ni = 0; ni < 4; ++ni)
          acc[mi][ni] = __builtin_amdgcn_mfma_f32_16x16x32_bf16(af[mi], bq[ni], acc[mi][ni], 0, 0, 0);
    }
    __syncthreads();
  }

  // ---- epilogue ----
#pragma unroll
  for (int mi = 0; mi < 4; ++mi) {
#pragma unroll
    for (int q = 0; q < 4; ++q) {
      int row = m0 + wr * 64 + mi * 16 + (lane >> 4) * 4 + q;
      if (row >= rows) continue;
      if constexpr (MODE == M_XG) {
        int e = p.list[row]; int sp = e >> 4, tt = e & 15;
        unsigned short* cr = p.Cb + ((size_t)(sp * 16 + tt)) * G4_;
#pragma unroll
        for (int ni = 0; ni < 4; ++ni) {
          int col = n0 + wc * 64 + ni * 16 + (lane & 15);
          cr[col] = f2bf(acc[mi][ni][q] + p.bias[col]);
        }
      } else if constexpr (MODE == M_XGB) {
        float* cr = p.C + (size_t)row * G4_;
#pragma unroll
        for (int ni = 0; ni < 4; ++ni) {
          int col = n0 + wc * 64 + ni * 16 + (lane & 15);
          cr[col] = acc[mi][ni][q] + p.bias[col];
        }
      } else if constexpr (MODE == M_QKV) {
        float* cr = p.C + (size_t)row * 2304;
#pragma unroll
        for (int ni = 0; ni < 4; ++ni) {
          int col = n0 + wc * 64 + ni * 16 + (lane & 15);
          cr[col] = acc[mi][ni][q] + p.bias[col];
        }
      } else if constexpr (MODE == M_OUTP) {
        float* cr = p.C + (size_t)row * H_;
#pragma unroll
        for (int ni = 0; ni < 4; ++ni) {
          int col = n0 + wc * 64 + ni * 16 + (lane & 15);
          cr[col] = acc[mi][ni][q] + p.bias[col] + p.resid[(size_t)row * H_ + col];
        }
      } else if constexpr (MODE == M_AP1) {
        unsigned short* cr = p.Cb + (size_t)row * H_;
#pragma unroll
        for (int ni = 0; ni < 4; ++ni) {
          int col = n0 + wc * 64 + ni * 16 + (lane & 15);
          cr[col] = f2bf(fmaxf(acc[mi][ni][q] + p.bias[col], 0.f));
        }
      } else {  // M_AP2: scatter to output token row
        int e = p.list[row]; int bt = e & 0xFFFFF;
        float* cr = p.C + (size_t)bt * H_;
#pragma unroll
        for (int ni = 0; ni < 4; ++ni) {
          int col = n0 + wc * 64 + ni * 16 + (lane & 15);
          cr[col] = acc[mi][ni][q] + p.bias[col];
        }
      }
    }
  }
}

// ---------------- backward (single-step) LSTM activation ----------------
__global__ void bwd_act(const float* __restrict__ gb, float* __restrict__ ea,
                        float* __restrict__ eo) {
  int idx = blockIdx.x * 256 + threadIdx.x;
  if (idx >= 2 * NS_ * HH_) return;
  int type = idx / (NS_ * HH_);
  int rem = idx - type * NS_ * HH_;
  int sp = rem / HH_, j = rem - sp * HH_;
  const float* g = gb + ((size_t)type * NS_ + sp) * G4_;
  float cb = sigf(g[j]) * tanhfast(g[2 * HH_ + j]);
  float hb = sigf(g[3 * HH_ + j]) * tanhfast(cb);
  (type ? eo : ea)[(size_t)sp * H_ + HH_ + j] = hb;
}

// ---------------- LSTM recurrence step: bf16 MFMA, gate-gathered B ----------------
// Block: 128 sorted spans (m) x 32 h-cols (jb), computing all 4 gates.
// Wave (2x2): wr over m (64), wc over 16-col halves; n-frag index == gate.
struct LP {
  const unsigned short* hr;   // read h buf  [2type][384][384] bf16
  unsigned short* hw;         // write h buf
  float* c;                   // c state sorted [2type][384][384] f32
  const unsigned short* xg_a; // bf16 [NS][16][1536]
  const unsigned short* xg_o;
  const unsigned short* whh_a;  // bf16 [1536][384]
  const unsigned short* whh_o;
  const int* ord; const int* slens;
  int t;
};

__global__ __launch_bounds__(256) void lstm_mfma(LP p) {
  const int type = blockIdx.z;
  const int m0 = blockIdx.x * 128;
  const int jb = blockIdx.y * 32;
  const int tid = threadIdx.x;
  const unsigned short* hr = p.hr + (size_t)type * 384 * 384;
  unsigned short* hw = p.hw + (size_t)type * 384 * 384;
  const int* slens = p.slens + type * NS_;

  if (slens[m0] <= p.t) {   // whole block inactive: carry h patch
    int r = tid >> 1, ch = tid & 1;
    const unsigned short* s = hr + (size_t)(m0 + r) * 384 + jb + ch * 16;
    unsigned short* d = hw + (size_t)(m0 + r) * 384 + jb + ch * 16;
    *(uint4*)d = *(const uint4*)s;
    *(uint4*)(d + 8) = *(const uint4*)(s + 8);
    return;
  }

  const unsigned short* xg = type ? p.xg_o : p.xg_a;
  const unsigned short* whh = type ? p.whh_o : p.whh_a;
  const int* ordt = p.ord + type * NS_;
  float* cst = p.c + (size_t)type * 384 * 384;

  __shared__ __align__(16) unsigned short As[128 * 64];
  __shared__ __align__(16) unsigned short Bs[128 * 64];

  const int ar = tid >> 1, kh = tid & 1;
  const unsigned short* arow = hr + (size_t)(m0 + ar) * 384;
  // gate-gathered B row: local r -> n_global = gate(r)*384 + jb + wcol(r)*16 + col(r)
  const int ng = ((ar >> 4) & 3) * HH_ + jb + (ar >> 6) * 16 + (ar & 15);
  const unsigned short* brow = whh + (size_t)ng * HH_;

  const int lane = tid & 63, wv = tid >> 6, wr = wv >> 1, wc = wv & 1;
  const int abase_r = wr * 64 + (lane & 15);
  const int bbase_r = wc * 64 + (lane & 15);
  const int kcol = lane >> 4;
  const int swz = (lane & 7) << 4;

  f32x4 acc[4][4];
#pragma unroll
  for (int mi = 0; mi < 4; ++mi)
#pragma unroll
    for (int ni = 0; ni < 4; ++ni) acc[mi][ni] = (f32x4){0.f, 0.f, 0.f, 0.f};

  for (int k0 = 0; k0 < HH_; k0 += 64) {
    const unsigned short* sa = arow + k0 + kh * 32;
    const unsigned short* sb = brow + k0 + kh * 32;
#pragma unroll
    for (int c = 0; c < 4; ++c) {
      *(uint4*)((char*)As + ar * 128 + ((((kh * 4 + c) * 16)) ^ ((ar & 7) << 4))) =
          *(const uint4*)(sa + c * 8);
      *(uint4*)((char*)Bs + ar * 128 + ((((kh * 4 + c) * 16)) ^ ((ar & 7) << 4))) =
          *(const uint4*)(sb + c * 8);
    }
    __syncthreads();
#pragma unroll
    for (int ks = 0; ks < 2; ++ks) {
      short8 af[4], bq[4];
#pragma unroll
      for (int i = 0; i < 4; ++i)
        af[i] = *(const short8*)((char*)As + (abase_r + i * 16) * 128 +
                                 (((ks * 4 + kcol) * 16) ^ swz));
#pragma unroll
      for (int i = 0; i < 4; ++i)
        bq[i] = *(const short8*)((char*)Bs + (bbase_r + i * 16) * 128 +
                                 (((ks * 4 + kcol) * 16) ^ swz));
#pragma unroll
      for (int mi = 0; mi < 4; ++mi)
#pragma unroll
        for (int ni = 0; ni < 4; ++ni)
          acc[mi][ni] = __builtin_amdgcn_mfma_f32_16x16x32_bf16(af[mi], bq[ni], acc[mi][ni], 0, 0, 0);
    }
    __syncthreads();
  }

  // epilogue: n-frag ni == gate; i/f/g/o in same lane/reg
  const int col = jb + wc * 16 + (lane & 15);
#pragma unroll
  for (int mi = 0; mi < 4; ++mi) {
#pragma unroll
    for (int q = 0; q < 4; ++q) {
      int row = m0 + wr * 64 + mi * 16 + (lane >> 4) * 4 + q;
      int sp = ordt[row];
      bool act = p.t < slens[row];
      const unsigned short* xr = xg + ((size_t)(sp * 16 + p.t)) * G4_;
      float gi = acc[mi][0][q] + bf2f(xr[col]);
      float gf = acc[mi][1][q] + bf2f(xr[HH_ + col]);
      float gg = acc[mi][2][q] + bf2f(xr[2 * HH_ + col]);
      float go = acc[mi][3][q] + bf2f(xr[3 * HH_ + col]);
      size_t hidx = (size_t)row * 384 + col;
      unsigned short hraw = hr[hidx];
      float co = cst[hidx];
      float cn = sigf(gf) * co + sigf(gi) * tanhfast(gg);
      float hn = sigf(go) * tanhfast(cn);
      hw[hidx] = act ? f2bf(hn) : hraw;
      if (act) cst[hidx] = cn;
    }
  }
}

// scatter final sorted h (bf16) into ea/eo forward half (f32)
__global__ void finalize_h(const unsigned short* __restrict__ hfin,
                           const int* __restrict__ ord,
                           float* __restrict__ ea, float* __restrict__ eo) {
  int idx = blockIdx.x * 256 + threadIdx.x;
  if (idx >= 2 * 384 * 384) return;
  int type = idx / (384 * 384);
  int rem = idx - type * 384 * 384;
  int srt = rem / 384, j = rem - srt * 384;
  int sp = ord[type * NS_ + srt];
  (type ? eo : ea)[(size_t)sp * H_ + j] =
      bf2f(hfin[(size_t)type * 384 * 384 + (size_t)srt * 384 + j]);
}

// ---------------- attention core: one (b, head) per block ----------------
__global__ __launch_bounds__(256) void attn_core(const float* __restrict__ qkv,
                                                 float* __restrict__ aot) {
  int b = blockIdx.x >> 3, h = blockIdx.x & 7;
  __shared__ float qs[24][97], ks[24][97], vs[24][97];
  __shared__ float sc[24][25];
  __shared__ float sinv[24];
  int tid = threadIdx.x;
  for (int idx = tid; idx < 24 * 96; idx += 256) {
    int s = idx / 96, d = idx - s * 96;
    size_t rb = ((size_t)(b * 24 + s)) * 2304 + h * 96 + d;
    qs[s][d] = qkv[rb];
    ks[s][d] = qkv[rb + H_];
    vs[s][d] = qkv[rb + 2 * H_];
  }
  __syncthreads();
  for (int pp = tid; pp < 576; pp += 256) {
    int qi = pp / 24, ki = pp - qi * 24;
    float a = 0.f;
    for (int d = 0; d < 96; ++d) a = fmaf(qs[qi][d], ks[ki][d], a);
    sc[qi][ki] = a * 0.10206207261596577f;
  }
  __syncthreads();
  if (tid < 24) {
    float m = -1e30f;
    for (int k2 = 0; k2 < 24; ++k2) m = fmaxf(m, sc[tid][k2]);
    float ssum = 0.f;
    for (int k2 = 0; k2 < 24; ++k2) { float e = __expf(sc[tid][k2] - m); sc[tid][k2] = e; ssum += e; }
    sinv[tid] = 1.f / ssum;
  }
  __syncthreads();
  for (int idx = tid; idx < 24 * 96; idx += 256) {
    int s = idx / 96, d = idx - s * 96;
    float a = 0.f;
    for (int k2 = 0; k2 < 24; ++k2) a = fmaf(sc[s][k2], vs[k2][d], a);
    aot[((size_t)(b * 24 + s)) * H_ + h * 96 + d] = a * sinv[s];
  }
}

// ---------------- layernorm over H per row ----------------
__global__ __launch_bounds__(256) void ln_k(const float* __restrict__ x,
                                            const float* __restrict__ g,
                                            const float* __restrict__ bb,
                                            float* __restrict__ dst) {
  int row = blockIdx.x;
  const float* xr = x + (size_t)row * H_;
  float vals[3];
  float s1 = 0.f, s2 = 0.f;
#pragma unroll
  for (int u = 0; u < 3; ++u) {
    float v = xr[threadIdx.x + 256 * u];
    vals[u] = v; s1 += v; s2 += v * v;
  }
  for (int o = 32; o > 0; o >>= 1) { s1 += __shfl_down(s1, o, 64); s2 += __shfl_down(s2, o, 64); }
  __shared__ float r1[4], r2[4];
  __shared__ float mu_s, rs_s;
  int w = threadIdx.x >> 6, lane = threadIdx.x & 63;
  if (lane == 0) { r1[w] = s1; r2[w] = s2; }
  __syncthreads();
  if (threadIdx.x == 0) {
    float t1 = r1[0] + r1[1] + r1[2] + r1[3];
    float t2 = r2[0] + r2[1] + r2[2] + r2[3];
    float mu = t1 / (float)H_;
    float var = t2 / (float)H_ - mu * mu;
    mu_s = mu; rs_s = rsqrtf(var + 1e-5f);
  }
  __syncthreads();
#pragma unroll
  for (int u = 0; u < 3; ++u) {
    int c = threadIdx.x + 256 * u;
    dst[(size_t)row * H_ + c] = (vals[u] - mu_s) * rs_s * g[c] + bb[c];
  }
}

}  // namespace

extern "C" void kernel_launch(void* const* d_in, const int* in_sizes, int n_in,
                              void* d_out, int out_size, void* d_ws, size_t ws_size,
                              hipStream_t stream) {
  (void)in_sizes; (void)n_in; (void)out_size; (void)ws_size;
  const float* hs = (const float*)d_in[0];
  const int* asp = (const int*)d_in[1];
  const int* osp = (const int*)d_in[2];
  const float* a_wih_f = (const float*)d_in[3];
  const float* a_whh_f = (const float*)d_in[4];
  const float* a_b_f   = (const float*)d_in[5];
  const float* a_wih_b = (const float*)d_in[6];
  const float* a_b_b   = (const float*)d_in[8];
  const float* o_wih_f = (const float*)d_in[9];
  const float* o_whh_f = (const float*)d_in[10];
  const float* o_b_f   = (const float*)d_in[11];
  const float* o_wih_b = (const float*)d_in[12];
  const float* o_b_b   = (const float*)d_in[14];
  const float* ao_in_w  = (const float*)d_in[15];
  const float* ao_in_b  = (const float*)d_in[16];
  const float* ao_out_w = (const float*)d_in[17];
  const float* ao_out_b = (const float*)d_in[18];
  const float* oa_in_w  = (const float*)d_in[19];
  const float* oa_in_b  = (const float*)d_in[20];
  const float* oa_out_w = (const float*)d_in[21];
  const float* oa_out_b = (const float*)d_in[22];
  const float* ln_a_g = (const float*)d_in[23];
  const float* ln_a_b = (const float*)d_in[24];
  const float* ln_o_g = (const float*)d_in[25];
  const float* ln_o_b = (const float*)d_in[26];
  const float* p_w1 = (const float*)d_in[27];
  const float* p_b1 = (const float*)d_in[28];
  const float* p_w2 = (const float*)d_in[29];
  const float* p_b2 = (const float*)d_in[30];
  float* out = (float*)d_out;

  char* ws = (char*)d_ws;
  unsigned short* WB = (unsigned short*)(ws + WB_B);
  unsigned short* xga = (unsigned short*)(ws + XGA_B);
  unsigned short* xgo = (unsigned short*)(ws + XGO_B);
  float* qkv = (float*)(ws + QKV_B);
  float* aot = (float*)(ws + AOT_B);
  float* rt  = (float*)(ws + RT_B);
  float* ea  = (float*)(ws + EA_B);
  float* eo  = (float*)(ws + EO_B);
  unsigned short* hb = (unsigned short*)(ws + HB_B);   // [2][2][384][384]
  float* cst = (float*)(ws + CST_B);
  float* gb  = (float*)(ws + QKV_B);                   // overlay (dead before attention)
  unsigned short* h1b = (unsigned short*)(ws + XGA_B); // overlay (xg dead after recurrence)
  int* I = (int*)(ws + INT_B);
  int* starts = I + I_STARTS;
  int* lens   = I + I_LENS;
  int* ord    = I + I_ORD;
  int* slens  = I + I_SLENS;
  int* xglist = I + I_XGLIST;
  int* toklist = I + I_TOKLIST;
  int* cnt    = I + I_CNT;

  // passthrough tokens
  hipMemcpyAsync(out, hs, (size_t)B_ * T_ * H_ * sizeof(float),
                 hipMemcpyDeviceToDevice, stream);
  hipMemsetAsync(cnt, 0, 4 * sizeof(int), stream);
  hipMemsetAsync(ws + HB_B, 0, (CST_B - HB_B) + 2ull * 384 * 384 * 4, stream);  // h bufs + c

  // weight prep (f32 -> bf16; p_w1/p_w2 transposed)
  {
    PREP pp;
    pp.j[0]  = {a_wih_f,  WB + W_AWIF,  1536 * 768, 0, 0, 0};
    pp.j[1]  = {o_wih_f,  WB + W_OWIF,  1536 * 768, 0, 0, 0};
    pp.j[2]  = {a_wih_b,  WB + W_AWIB,  1536 * 768, 0, 0, 0};
    pp.j[3]  = {o_wih_b,  WB + W_OWIB,  1536 * 768, 0, 0, 0};
    pp.j[4]  = {a_whh_f,  WB + W_AWHH,  1536 * 384, 0, 0, 0};
    pp.j[5]  = {o_whh_f,  WB + W_OWHH,  1536 * 384, 0, 0, 0};
    pp.j[6]  = {ao_in_w,  WB + W_AOIN,  2 * 2304 * 768, 0, 0, 0};
    pp.j[7]  = {oa_in_w,  WB + W_OAIN,  2 * 2304 * 768, 0, 0, 0};
    pp.j[8]  = {ao_out_w, WB + W_AOOUT, 2 * 768 * 768, 0, 0, 0};
    pp.j[9]  = {oa_out_w, WB + W_OAOUT, 2 * 768 * 768, 0, 0, 0};
    pp.j[10] = {p_w1,     WB + W_PW1T,  1536 * 768, 1536, 768, 1};
    pp.j[11] = {p_w2,     WB + W_PW2T,  768 * 768,  768,  768, 1};
    prep_w<<<dim3(512, 12), 256, 0, stream>>>(pp);
  }

  span_meta<<<3, 256, 0, stream>>>(asp, osp, starts, lens, xglist, cnt);
  sort_spans<<<2, 384, 0, stream>>>(lens, ord, slens);
  cov_build<<<3, 256, 0, stream>>>(asp, osp, toklist, cnt + 2);

  // LSTM input projections -> xg bf16
  {
    GP g{}; g.A = hs; g.Wb = WB + W_AWIF; g.bias = a_b_f; g.Cb = xga;
    g.list = xglist; g.cnt = cnt; g.starts = starts; g.K = H_;
    mgemm<M_XG><<<dim3(48, 12), 256, 0, stream>>>(g);
  }
  {
    GP g{}; g.A = hs; g.Wb = WB + W_OWIF; g.bias = o_b_f; g.Cb = xgo;
    g.list = xglist + MAXTOK_; g.cnt = cnt + 1; g.starts = starts + NS_; g.K = H_;
    mgemm<M_XG><<<dim3(48, 12), 256, 0, stream>>>(g);
  }
  {
    GP g{}; g.A = hs; g.Wb = WB + W_AWIB; g.bias = a_b_b; g.C = gb;
    g.starts = starts; g.lens = lens; g.K = H_;
    mgemm<M_XGB><<<dim3(3, 12), 256, 0, stream>>>(g);
  }
  {
    GP g{}; g.A = hs; g.Wb = WB + W_OWIB; g.bias = o_b_b; g.C = gb + (size_t)NS_ * G4_;
    g.starts = starts + NS_; g.lens = lens + NS_; g.K = H_;
    mgemm<M_XGB><<<dim3(3, 12), 256, 0, stream>>>(g);
  }
  bwd_act<<<(2 * NS_ * HH_ + 255) / 256, 256, 0, stream>>>(gb, ea, eo);

  // 16-step recurrence, h bf16 double-buffered in sorted order
  for (int t = 0; t < 16; ++t) {
    LP lp{};
    lp.hr = hb + (size_t)(t & 1) * 2 * 384 * 384;
    lp.hw = hb + (size_t)((t + 1) & 1) * 2 * 384 * 384;
    lp.c = cst;
    lp.xg_a = xga; lp.xg_o = xgo;
    lp.whh_a = WB + W_AWHH; lp.whh_o = WB + W_OWHH;
    lp.ord = ord; lp.slens = slens; lp.t = t;
    lstm_mfma<<<dim3(3, 12, 2), 256, 0, stream>>>(lp);
  }
  finalize_h<<<(2 * 384 * 384 + 255) / 256, 256, 0, stream>>>(hb, ord, ea, eo);

  // L=2 layers of cross attention
  for (int l = 0; l < 2; ++l) {
    for (int dir = 0; dir < 2; ++dir) {
      float* q  = dir ? eo : ea;
      float* kv = dir ? ea : eo;
      const unsigned short* inw = WB + (dir ? W_OAIN : W_AOIN) + (size_t)l * 2304 * 768;
      const float* inb = (dir ? oa_in_b : ao_in_b) + (size_t)l * 3 * H_;
      const unsigned short* ow = WB + (dir ? W_OAOUT : W_AOOUT) + (size_t)l * 768 * 768;
      const float* ob = (dir ? oa_out_b : ao_out_b) + (size_t)l * H_;
      const float* lg = (dir ? ln_o_g : ln_a_g) + (size_t)l * H_;
      const float* lb = (dir ? ln_o_b : ln_a_b) + (size_t)l * H_;
      {
        GP g{}; g.A = q; g.A2 = kv; g.Wb = inw; g.bias = inb; g.C = qkv; g.K = H_;
        mgemm<M_QKV><<<dim3(3, 18), 256, 0, stream>>>(g);
      }
      attn_core<<<128, 256, 0, stream>>>(qkv, aot);
      {
        GP g{}; g.A = aot; g.Wb = ow; g.bias = ob; g.resid = q; g.C = rt; g.K = H_;
        mgemm<M_OUTP><<<dim3(3, 6), 256, 0, stream>>>(g);
      }
      ln_k<<<NS_, 256, 0, stream>>>(rt, lg, lb, q);
    }
  }

  // apply spans: aspect pass then opinion pass
  for (int type = 0; type < 2; ++type) {
    {
      GP g{}; g.A = out; g.A2 = type ? eo : ea; g.Wb = WB + W_PW1T; g.bias = p_b1; g.Cb = h1b;
      g.list = toklist + (size_t)type * MAXTOK_; g.cnt = cnt + 2 + type; g.K = 2 * H_;
      mgemm<M_AP1><<<dim3(48, 6), 256, 0, stream>>>(g);
    }
    {
      GP g{}; g.Ab = h1b; g.Wb = WB + W_PW2T; g.bias = p_b2; g.C = out;
      g.list = toklist + (size_t)type * MAXTOK_; g.cnt = cnt + 2 + type; g.K = H_;
      mgemm<M_AP2><<<dim3(48, 6), 256, 0, stream>>>(g);
    }
  }
}

// Round 7
// 1283.410 us; speedup vs baseline: 2.2388x; 1.1837x over previous
//
#include <hip/hip_runtime.h>
#include <cstddef>
#include <cstdint>

#define DI __device__ __forceinline__

namespace {

typedef short short8 __attribute__((ext_vector_type(8)));
typedef float f32x4 __attribute__((ext_vector_type(4)));

constexpr int B_ = 16, T_ = 2048, H_ = 768, HH_ = 384, NSPAN_ = 24;
constexpr int NS_ = B_ * NSPAN_;          // 384 spans per type
constexpr int G4_ = 4 * HH_;              // 1536 gate width
constexpr int WMAX_ = 16;
constexpr int MAXTOK_ = NS_ * WMAX_;      // 6144 max gathered rows

// ---------------- workspace layout (bytes) ----------------
constexpr size_t W_AWIF = 0;               // 1536x768
constexpr size_t W_OWIF = 1179648;
constexpr size_t W_AWIB = 2359296;
constexpr size_t W_OWIB = 3538944;
constexpr size_t W_AWHH = 4718592;         // 1536x384
constexpr size_t W_OWHH = 5308416;
constexpr size_t W_AOIN = 5898240;         // 2x2304x768
constexpr size_t W_OAIN = 9437184;
constexpr size_t W_AOOUT = 12976128;       // 2x768x768
constexpr size_t W_OAOUT = 14155776;
constexpr size_t W_PW1T = 15335424;        // 768x1536 (transposed)
constexpr size_t W_PW2T = 16515072;        // 768x768  (transposed)
constexpr size_t W_TOTEL = 17104896;

constexpr size_t WB_B   = 0;
constexpr size_t WB_SZ  = W_TOTEL * 2;
constexpr size_t XGSZ_B = (size_t)NS_ * 16 * G4_ * 2;     // bf16
constexpr size_t XGA_B  = WB_B + WB_SZ;
constexpr size_t XGO_B  = XGA_B + XGSZ_B;
constexpr size_t QKV_B  = XGO_B + XGSZ_B;                 // f32 NS x 2304
constexpr size_t AOT_B  = QKV_B + (size_t)NS_ * 2304 * 4;
constexpr size_t RT_B   = AOT_B + (size_t)NS_ * H_ * 4;
constexpr size_t EA_B   = RT_B + (size_t)NS_ * H_ * 4;
constexpr size_t EO_B   = EA_B + (size_t)NS_ * H_ * 4;
constexpr size_t HB_B   = EO_B + (size_t)NS_ * H_ * 4;    // h bufs bf16 [2][2][384][384]
constexpr size_t CST_B  = HB_B + 2ull * 2 * 384 * 384 * 2;
constexpr size_t INT_B  = CST_B + 2ull * 384 * 384 * 4;
// ints (element offsets from INT_B)
constexpr size_t I_STARTS = 0;
constexpr size_t I_LENS   = I_STARTS + 2 * NS_;
constexpr size_t I_ORD    = I_LENS + 2 * NS_;
constexpr size_t I_SLENS  = I_ORD + 2 * NS_;
constexpr size_t I_XGLIST = I_SLENS + 2 * NS_;
constexpr size_t I_TOKLIST = I_XGLIST + 2 * MAXTOK_;
constexpr size_t I_CNT    = I_TOKLIST + 2 * MAXTOK_;      // [xg_a, xg_o, tok_a, tok_o]

DI float sigf(float x) { return 1.f / (1.f + __expf(-x)); }
DI float tanhfast(float x) {
  x = fminf(fmaxf(x, -15.f), 15.f);
  float e = __expf(2.f * x);
  return (e - 1.f) / (e + 1.f);
}
DI unsigned short f2bf(float f) {
  unsigned u = __float_as_uint(f);
  return (unsigned short)((u + 0x7fffu + ((u >> 16) & 1u)) >> 16);
}
DI unsigned pk2(float lo, float hi) {
  return (unsigned)f2bf(lo) | ((unsigned)f2bf(hi) << 16);
}
DI float bf2f(unsigned short u) { return __uint_as_float(((unsigned)u) << 16); }

// ---------------- weight prep: f32 -> bf16 (+LDS-tiled transpose) ----------------
struct PJ { const float* src; unsigned short* dst; int n; int R; int C; int tr; };
struct PREP { PJ j[12]; };

__global__ __launch_bounds__(256) void prep_w(PREP pp) {
  PJ job = pp.j[blockIdx.y];
  if (!job.tr) {
    int stride = gridDim.x * blockDim.x;
    int g = blockIdx.x * blockDim.x + threadIdx.x;
    int n4 = job.n >> 2;
    for (int i = g; i < n4; i += stride) {
      float4 v = ((const float4*)job.src)[i];
      ushort4 o;
      o.x = f2bf(v.x); o.y = f2bf(v.y); o.z = f2bf(v.z); o.w = f2bf(v.w);
      ((ushort4*)job.dst)[i] = o;
    }
  } else {
    // src R x C (f32) -> dst C x R (bf16), 32x32 LDS tiles
    __shared__ unsigned short tile[32][34];
    int R = job.R, C = job.C;
    int tcn = C >> 5, trn = R >> 5;
    int tx = threadIdx.x & 31, ty = threadIdx.x >> 5;   // 32 x 8
    for (int tid2 = blockIdx.x; tid2 < trn * tcn; tid2 += gridDim.x) {
      int trr = (tid2 / tcn) << 5, tcc = (tid2 % tcn) << 5;
      __syncthreads();
#pragma unroll
      for (int k = 0; k < 4; ++k)
        tile[ty + 8 * k][tx] = f2bf(job.src[(size_t)(trr + ty + 8 * k) * C + tcc + tx]);
      __syncthreads();
#pragma unroll
      for (int k = 0; k < 4; ++k)
        job.dst[(size_t)(tcc + ty + 8 * k) * R + trr + tx] = tile[tx][ty + 8 * k];
    }
  }
}

// ---------------- fused span metadata: scans instead of global atomics ----------------
__global__ __launch_bounds__(768) void span_prep(
    const int* __restrict__ asp, const int* __restrict__ osp,
    int* __restrict__ starts, int* __restrict__ lens,
    int* __restrict__ ord, int* __restrict__ slens,
    int* __restrict__ xglist, int* __restrict__ toklist, int* __restrict__ cnt) {
  int tid = threadIdx.x;                       // 0..767 = type*384 + sp
  int type = tid / NS_, sp = tid - type * NS_;
  const int* spans = type ? osp : asp;
  int s0 = spans[2 * sp], s1 = spans[2 * sp + 1];
  int st = min(max(s0, 0), T_ - 1);
  int en = min(max(s1, st + 1), T_);
  int ln = min(en - st, WMAX_);
  starts[tid] = st;
  lens[tid] = ln;
  int clo = max(s0, 0), chi = min(s1, T_);
  int cln = max(chi - clo, 0);

  __shared__ int sx[768];
  __shared__ int t0s, t0c;
  // scan 1: xg lens -> xglist placement
  sx[tid] = ln;
  __syncthreads();
  for (int off = 1; off < 768; off <<= 1) {
    int v = (tid >= off) ? sx[tid - off] : 0;
    __syncthreads();
    sx[tid] += v;
    __syncthreads();
  }
  if (tid == NS_ - 1) t0s = sx[tid];
  __syncthreads();
  {
    int base = sx[tid] - ln - (type ? t0s : 0);
    for (int t = 0; t < ln; ++t) {
      int pos = base + t;
      if (pos < MAXTOK_) xglist[type * MAXTOK_ + pos] = (sp << 4) | t;
    }
    if (tid == NS_ - 1) cnt[0] = sx[tid];
    if (tid == 767) cnt[1] = sx[767] - t0s;
  }
  __syncthreads();
  // scan 2: coverage lens -> toklist placement
  sx[tid] = cln;
  __syncthreads();
  for (int off = 1; off < 768; off <<= 1) {
    int v = (tid >= off) ? sx[tid - off] : 0;
    __syncthreads();
    sx[tid] += v;
    __syncthreads();
  }
  if (tid == NS_ - 1) t0c = sx[tid];
  __syncthreads();
  {
    int base = sx[tid] - cln - (type ? t0c : 0);
    int b = sp / NSPAN_, slocal = sp - b * NSPAN_;
    for (int t = 0; t < cln; ++t) {
      int pos = base + t;
      if (pos < MAXTOK_) toklist[type * MAXTOK_ + pos] = (b * T_ + clo + t) | (slocal << 20);
    }
    if (tid == NS_ - 1) cnt[2] = sx[tid];
    if (tid == 767) cnt[3] = sx[767] - t0c;
  }
  // counting sort by len desc per type (LDS atomics only)
  __shared__ int hist[2][WMAX_], hoff[2][WMAX_];
  if (tid < 2 * WMAX_) hist[tid / WMAX_][tid % WMAX_] = 0;
  __syncthreads();
  atomicAdd(&hist[type][WMAX_ - ln], 1);
  __syncthreads();
  if (tid < 2) {
    int a = 0;
    for (int bkt = 0; bkt < WMAX_; ++bkt) { hoff[tid][bkt] = a; a += hist[tid][bkt]; }
  }
  __syncthreads();
  int pos = atomicAdd(&hoff[type][WMAX_ - ln], 1);
  ord[type * NS_ + pos] = sp;
  slens[type * NS_ + pos] = ln;
}

// ---------------- bf16 MFMA GEMM, 128x128x64 tile, 4 waves ----------------
enum { M_XG = 0, M_QKV = 2, M_OUTP = 3, M_AP1 = 4, M_AP2 = 5 };

struct GP {
  const float* A;
  const float* A2;
  const unsigned short* Wb;   // bf16 W [N][K]
  const unsigned short* Ab;   // bf16 A (AP2)
  const float* bias;
  const float* resid;
  float* C;
  unsigned short* Cb;
  const int* list;
  const int* cnt;
  const int* starts;
  int K;
};

template <int MODE>
__global__ __launch_bounds__(256) void mgemm(GP p) {
  __shared__ __align__(16) unsigned short As[128 * 64];
  __shared__ __align__(16) unsigned short Bs[128 * 64];
  const int tid = threadIdx.x;
  const int m0 = blockIdx.x * 128, n0 = blockIdx.y * 128;
  int rows = NS_;
  if constexpr (MODE == M_XG || MODE == M_AP1 || MODE == M_AP2) rows = min(*p.cnt, MAXTOK_);
  if (m0 >= rows) return;

  const int ar = tid >> 1, kh = tid & 1;
  const int lr = m0 + ar;
  const bool aok = lr < rows;
  const float* aptr = nullptr;
  const float* aptr2 = nullptr;
  const unsigned short* abptr = nullptr;
  if (aok) {
    if constexpr (MODE == M_XG) {
      int e = p.list[lr]; int sp = e >> 4, tt = e & 15;
      int srow = min(p.starts[sp] + tt, T_ - 1);
      aptr = p.A + ((size_t)((sp / NSPAN_) * T_ + srow)) * H_;
    } else if constexpr (MODE == M_QKV) {
      aptr = ((n0 < H_) ? p.A : p.A2) + (size_t)lr * H_;
    } else if constexpr (MODE == M_OUTP) {
      aptr = p.A + (size_t)lr * H_;
    } else if constexpr (MODE == M_AP1) {
      int e = p.list[lr]; int bt = e & 0xFFFFF; int s = e >> 20;
      aptr = p.A + (size_t)bt * H_;
      aptr2 = p.A2 + ((size_t)((bt >> 11) * NSPAN_ + s)) * H_;
    } else {  // M_AP2
      abptr = p.Ab + (size_t)lr * H_;
    }
  }
  const unsigned short* brow = p.Wb + (size_t)(n0 + ar) * p.K;

  const int lane = tid & 63, wv = tid >> 6, wr = wv >> 1, wc = wv & 1;
  const int abase_r = wr * 64 + (lane & 15);
  const int bbase_r = wc * 64 + (lane & 15);
  const int kcol = lane >> 4;
  const int swz = (lane & 7) << 4;

  f32x4 acc[4][4];
#pragma unroll
  for (int mi = 0; mi < 4; ++mi)
#pragma unroll
    for (int ni = 0; ni < 4; ++ni) acc[mi][ni] = (f32x4){0.f, 0.f, 0.f, 0.f};

  for (int k0 = 0; k0 < p.K; k0 += 64) {
    if constexpr (MODE == M_AP2) {
      if (aok) {
        const unsigned short* s = abptr + k0 + kh * 32;
#pragma unroll
        for (int c = 0; c < 4; ++c)
          *(uint4*)((char*)As + ar * 128 + ((((kh * 4 + c) * 16)) ^ ((ar & 7) << 4))) =
              *(const uint4*)(s + c * 8);
      }
    } else {
      if (aok) {
#pragma unroll
        for (int c = 0; c < 4; ++c) {
          int kg = k0 + kh * 32 + c * 8;
          const float* s;
          if constexpr (MODE == M_AP1) s = (kg < H_) ? (aptr + kg) : (aptr2 + (kg - H_));
          else s = aptr + kg;
          float4 u = *(const float4*)s;
          float4 v = *(const float4*)(s + 4);
          uint4 w;
          w.x = pk2(u.x, u.y); w.y = pk2(u.z, u.w);
          w.z = pk2(v.x, v.y); w.w = pk2(v.z, v.w);
          *(uint4*)((char*)As + ar * 128 + ((((kh * 4 + c) * 16)) ^ ((ar & 7) << 4))) = w;
        }
      }
    }
    {
      const unsigned short* s = brow + k0 + kh * 32;
#pragma unroll
      for (int c = 0; c < 4; ++c)
        *(uint4*)((char*)Bs + ar * 128 + ((((kh * 4 + c) * 16)) ^ ((ar & 7) << 4))) =
            *(const uint4*)(s + c * 8);
    }
    __syncthreads();
#pragma unroll
    for (int ks = 0; ks < 2; ++ks) {
      short8 af[4], bq[4];
#pragma unroll
      for (int i = 0; i < 4; ++i)
        af[i] = *(const short8*)((char*)As + (abase_r + i * 16) * 128 +
                                 (((ks * 4 + kcol) * 16) ^ swz));
#pragma unroll
      for (int i = 0; i < 4; ++i)
        bq[i] = *(const short8*)((char*)Bs + (bbase_r + i * 16) * 128 +
                                 (((ks * 4 + kcol) * 16) ^ swz));
#pragma unroll
      for (int mi = 0; mi < 4; ++mi)
#pragma unroll
        for (int ni = 0; ni < 4; ++ni)
          acc[mi][ni] = __builtin_amdgcn_mfma_f32_16x16x32_bf16(af[mi], bq[ni], acc[mi][ni], 0, 0, 0);
    }
    __syncthreads();
  }

#pragma unroll
  for (int mi = 0; mi < 4; ++mi) {
#pragma unroll
    for (int q = 0; q < 4; ++q) {
      int row = m0 + wr * 64 + mi * 16 + (lane >> 4) * 4 + q;
      if (row >= rows) continue;
      if constexpr (MODE == M_XG) {
        int e = p.list[row]; int sp = e >> 4, tt = e & 15;
        unsigned short* cr = p.Cb + ((size_t)(sp * 16 + tt)) * G4_;
#pragma unroll
        for (int ni = 0; ni < 4; ++ni) {
          int col = n0 + wc * 64 + ni * 16 + (lane & 15);
          cr[col] = f2bf(acc[mi][ni][q] + p.bias[col]);
        }
      } else if constexpr (MODE == M_QKV) {
        float* cr = p.C + (size_t)row * 2304;
#pragma unroll
        for (int ni = 0; ni < 4; ++ni) {
          int col = n0 + wc * 64 + ni * 16 + (lane & 15);
          cr[col] = acc[mi][ni][q] + p.bias[col];
        }
      } else if constexpr (MODE == M_OUTP) {
        float* cr = p.C + (size_t)row * H_;
#pragma unroll
        for (int ni = 0; ni < 4; ++ni) {
          int col = n0 + wc * 64 + ni * 16 + (lane & 15);
          cr[col] = acc[mi][ni][q] + p.bias[col] + p.resid[(size_t)row * H_ + col];
        }
      } else if constexpr (MODE == M_AP1) {
        unsigned short* cr = p.Cb + (size_t)row * H_;
#pragma unroll
        for (int ni = 0; ni < 4; ++ni) {
          int col = n0 + wc * 64 + ni * 16 + (lane & 15);
          cr[col] = f2bf(fmaxf(acc[mi][ni][q] + p.bias[col], 0.f));
        }
      } else {  // M_AP2
        int e = p.list[row]; int bt = e & 0xFFFFF;
        float* cr = p.C + (size_t)bt * H_;
#pragma unroll
        for (int ni = 0; ni < 4; ++ni) {
          int col = n0 + wc * 64 + ni * 16 + (lane & 15);
          cr[col] = acc[mi][ni][q] + p.bias[col];
        }
      }
    }
  }
}

// ---------------- backward-LSTM: gate-gathered MFMA, activation fused ----------------
struct XBP {
  const float* hs;
  const unsigned short* wa; const unsigned short* wo;  // bf16 [1536][768]
  const float* ba; const float* bo;
  float* ea; float* eo;
  const int* starts; const int* lens;
};

__global__ __launch_bounds__(256) void xgb_mfma(XBP p) {
  const int type = blockIdx.z;
  const int m0 = blockIdx.x * 128, jb = blockIdx.y * 32;
  const int tid = threadIdx.x;
  const unsigned short* wb = type ? p.wo : p.wa;
  const float* bias = type ? p.bo : p.ba;
  const int* starts = p.starts + type * NS_;
  const int* lens = p.lens + type * NS_;
  float* dst = type ? p.eo : p.ea;

  __shared__ __align__(16) unsigned short As[128 * 64];
  __shared__ __align__(16) unsigned short Bs[128 * 64];

  const int ar = tid >> 1, kh = tid & 1;
  const int spA = m0 + ar;
  int srow = min(max(starts[spA] + lens[spA] - 1, 0), T_ - 1);
  const float* aptr = p.hs + ((size_t)((spA / NSPAN_) * T_ + srow)) * H_;
  const int ng = ((ar >> 4) & 3) * HH_ + jb + (ar >> 6) * 16 + (ar & 15);
  const unsigned short* brow = wb + (size_t)ng * H_;

  const int lane = tid & 63, wv = tid >> 6, wr = wv >> 1, wc = wv & 1;
  const int abase_r = wr * 64 + (lane & 15);
  const int bbase_r = wc * 64 + (lane & 15);
  const int kcol = lane >> 4;
  const int swz = (lane & 7) << 4;

  f32x4 acc[4][4];
#pragma unroll
  for (int mi = 0; mi < 4; ++mi)
#pragma unroll
    for (int ni = 0; ni < 4; ++ni) acc[mi][ni] = (f32x4){0.f, 0.f, 0.f, 0.f};

  for (int k0 = 0; k0 < H_; k0 += 64) {
#pragma unroll
    for (int c = 0; c < 4; ++c) {
      const float* s = aptr + k0 + kh * 32 + c * 8;
      float4 u = *(const float4*)s;
      float4 v = *(const float4*)(s + 4);
      uint4 w;
      w.x = pk2(u.x, u.y); w.y = pk2(u.z, u.w);
      w.z = pk2(v.x, v.y); w.w = pk2(v.z, v.w);
      *(uint4*)((char*)As + ar * 128 + ((((kh * 4 + c) * 16)) ^ ((ar & 7) << 4))) = w;
      *(uint4*)((char*)Bs + ar * 128 + ((((kh * 4 + c) * 16)) ^ ((ar & 7) << 4))) =
          *(const uint4*)(brow + k0 + kh * 32 + c * 8);
    }
    __syncthreads();
#pragma unroll
    for (int ks = 0; ks < 2; ++ks) {
      short8 af[4], bq[4];
#pragma unroll
      for (int i = 0; i < 4; ++i)
        af[i] = *(const short8*)((char*)As + (abase_r + i * 16) * 128 +
                                 (((ks * 4 + kcol) * 16) ^ swz));
#pragma unroll
      for (int i = 0; i < 4; ++i)
        bq[i] = *(const short8*)((char*)Bs + (bbase_r + i * 16) * 128 +
                                 (((ks * 4 + kcol) * 16) ^ swz));
#pragma unroll
      for (int mi = 0; mi < 4; ++mi)
#pragma unroll
        for (int ni = 0; ni < 4; ++ni)
          acc[mi][ni] = __builtin_amdgcn_mfma_f32_16x16x32_bf16(af[mi], bq[ni], acc[mi][ni], 0, 0, 0);
    }
    __syncthreads();
  }

  const int col = jb + wc * 16 + (lane & 15);
#pragma unroll
  for (int mi = 0; mi < 4; ++mi) {
#pragma unroll
    for (int q = 0; q < 4; ++q) {
      int row = m0 + wr * 64 + mi * 16 + (lane >> 4) * 4 + q;
      float gi = acc[mi][0][q] + bias[col];
      float gg = acc[mi][2][q] + bias[2 * HH_ + col];
      float go = acc[mi][3][q] + bias[3 * HH_ + col];
      float cb = sigf(gi) * tanhfast(gg);
      float hb = sigf(go) * tanhfast(cb);
      dst[(size_t)row * H_ + HH_ + col] = hb;
    }
  }
}

// ---------------- LSTM recurrence step: bf16 MFMA, gate-gathered B ----------------
struct LP {
  const unsigned short* hr;
  unsigned short* hw;
  float* c;
  const unsigned short* xg_a;
  const unsigned short* xg_o;
  const unsigned short* whh_a;
  const unsigned short* whh_o;
  const int* ord; const int* slens;
  int t;
};

__global__ __launch_bounds__(256) void lstm_mfma(LP p) {
  const int type = blockIdx.z;
  const int m0 = blockIdx.x * 128;
  const int jb = blockIdx.y * 32;
  const int tid = threadIdx.x;
  const unsigned short* hr = p.hr + (size_t)type * 384 * 384;
  unsigned short* hw = p.hw + (size_t)type * 384 * 384;
  const int* slens = p.slens + type * NS_;

  int maxlen = slens[m0];
  if (maxlen <= p.t) {
    if (maxlen == p.t) {   // became inactive this step: carry once; both bufs final after
      int r = tid >> 1, ch = tid & 1;
      const unsigned short* s = hr + (size_t)(m0 + r) * 384 + jb + ch * 16;
      unsigned short* d = hw + (size_t)(m0 + r) * 384 + jb + ch * 16;
      *(uint4*)d = *(const uint4*)s;
      *(uint4*)(d + 8) = *(const uint4*)(s + 8);
    }
    return;
  }

  const unsigned short* xg = type ? p.xg_o : p.xg_a;
  const unsigned short* whh = type ? p.whh_o : p.whh_a;
  const int* ordt = p.ord + type * NS_;
  float* cst = p.c + (size_t)type * 384 * 384;

  __shared__ __align__(16) unsigned short As[128 * 64];
  __shared__ __align__(16) unsigned short Bs[128 * 64];

  const int ar = tid >> 1, kh = tid & 1;
  const unsigned short* arow = hr + (size_t)(m0 + ar) * 384;
  const int ng = ((ar >> 4) & 3) * HH_ + jb + (ar >> 6) * 16 + (ar & 15);
  const unsigned short* brow = whh + (size_t)ng * HH_;

  const int lane = tid & 63, wv = tid >> 6, wr = wv >> 1, wc = wv & 1;
  const int abase_r = wr * 64 + (lane & 15);
  const int bbase_r = wc * 64 + (lane & 15);
  const int kcol = lane >> 4;
  const int swz = (lane & 7) << 4;

  f32x4 acc[4][4];
#pragma unroll
  for (int mi = 0; mi < 4; ++mi)
#pragma unroll
    for (int ni = 0; ni < 4; ++ni) acc[mi][ni] = (f32x4){0.f, 0.f, 0.f, 0.f};

  for (int k0 = 0; k0 < HH_; k0 += 64) {
    const unsigned short* sa = arow + k0 + kh * 32;
    const unsigned short* sb = brow + k0 + kh * 32;
#pragma unroll
    for (int c = 0; c < 4; ++c) {
      *(uint4*)((char*)As + ar * 128 + ((((kh * 4 + c) * 16)) ^ ((ar & 7) << 4))) =
          *(const uint4*)(sa + c * 8);
      *(uint4*)((char*)Bs + ar * 128 + ((((kh * 4 + c) * 16)) ^ ((ar & 7) << 4))) =
          *(const uint4*)(sb + c * 8);
    }
    __syncthreads();
#pragma unroll
    for (int ks = 0; ks < 2; ++ks) {
      short8 af[4], bq[4];
#pragma unroll
      for (int i = 0; i < 4; ++i)
        af[i] = *(const short8*)((char*)As + (abase_r + i * 16) * 128 +
                                 (((ks * 4 + kcol) * 16) ^ swz));
#pragma unroll
      for (int i = 0; i < 4; ++i)
        bq[i] = *(const short8*)((char*)Bs + (bbase_r + i * 16) * 128 +
                                 (((ks * 4 + kcol) * 16) ^ swz));
#pragma unroll
      for (int mi = 0; mi < 4; ++mi)
#pragma unroll
        for (int ni = 0; ni < 4; ++ni)
          acc[mi][ni] = __builtin_amdgcn_mfma_f32_16x16x32_bf16(af[mi], bq[ni], acc[mi][ni], 0, 0, 0);
    }
    __syncthreads();
  }

  const int col = jb + wc * 16 + (lane & 15);
#pragma unroll
  for (int mi = 0; mi < 4; ++mi) {
#pragma unroll
    for (int q = 0; q < 4; ++q) {
      int row = m0 + wr * 64 + mi * 16 + (lane >> 4) * 4 + q;
      int sp = ordt[row];
      bool act = p.t < slens[row];
      const unsigned short* xr = xg + ((size_t)(sp * 16 + p.t)) * G4_;
      float gi = acc[mi][0][q] + bf2f(xr[col]);
      float gf = acc[mi][1][q] + bf2f(xr[HH_ + col]);
      float gg = acc[mi][2][q] + bf2f(xr[2 * HH_ + col]);
      float go = acc[mi][3][q] + bf2f(xr[3 * HH_ + col]);
      size_t hidx = (size_t)row * 384 + col;
      unsigned short hraw = hr[hidx];
      float co = cst[hidx];
      float cn = sigf(gf) * co + sigf(gi) * tanhfast(gg);
      float hn = sigf(go) * tanhfast(cn);
      hw[hidx] = act ? f2bf(hn) : hraw;
      if (act) cst[hidx] = cn;
    }
  }
}

// scatter final sorted h (bf16) into ea/eo forward half (f32)
__global__ void finalize_h(const unsigned short* __restrict__ hfin,
                           const int* __restrict__ ord,
                           float* __restrict__ ea, float* __restrict__ eo) {
  int idx = blockIdx.x * 256 + threadIdx.x;
  if (idx >= 2 * 384 * 384) return;
  int type = idx / (384 * 384);
  int rem = idx - type * 384 * 384;
  int srt = rem / 384, j = rem - srt * 384;
  int sp = ord[type * NS_ + srt];
  (type ? eo : ea)[(size_t)sp * H_ + j] =
      bf2f(hfin[(size_t)type * 384 * 384 + (size_t)srt * 384 + j]);
}

// ---------------- attention core: one (b, head) per block ----------------
__global__ __launch_bounds__(256) void attn_core(const float* __restrict__ qkv,
                                                 float* __restrict__ aot) {
  int b = blockIdx.x >> 3, h = blockIdx.x & 7;
  __shared__ float qs[24][97], ks[24][97], vs[24][97];
  __shared__ float sc[24][25];
  __shared__ float sinv[24];
  int tid = threadIdx.x;
  for (int idx = tid; idx < 24 * 96; idx += 256) {
    int s = idx / 96, d = idx - s * 96;
    size_t rb = ((size_t)(b * 24 + s)) * 2304 + h * 96 + d;
    qs[s][d] = qkv[rb];
    ks[s][d] = qkv[rb + H_];
    vs[s][d] = qkv[rb + 2 * H_];
  }
  __syncthreads();
  for (int pp = tid; pp < 576; pp += 256) {
    int qi = pp / 24, ki = pp - qi * 24;
    float a = 0.f;
    for (int d = 0; d < 96; ++d) a = fmaf(qs[qi][d], ks[ki][d], a);
    sc[qi][ki] = a * 0.10206207261596577f;
  }
  __syncthreads();
  if (tid < 24) {
    float m = -1e30f;
    for (int k2 = 0; k2 < 24; ++k2) m = fmaxf(m, sc[tid][k2]);
    float ssum = 0.f;
    for (int k2 = 0; k2 < 24; ++k2) { float e = __expf(sc[tid][k2] - m); sc[tid][k2] = e; ssum += e; }
    sinv[tid] = 1.f / ssum;
  }
  __syncthreads();
  for (int idx = tid; idx < 24 * 96; idx += 256) {
    int s = idx / 96, d = idx - s * 96;
    float a = 0.f;
    for (int k2 = 0; k2 < 24; ++k2) a = fmaf(sc[s][k2], vs[k2][d], a);
    aot[((size_t)(b * 24 + s)) * H_ + h * 96 + d] = a * sinv[s];
  }
}

// ---------------- layernorm over H per row ----------------
__global__ __launch_bounds__(256) void ln_k(const float* __restrict__ x,
                                            const float* __restrict__ g,
                                            const float* __restrict__ bb,
                                            float* __restrict__ dst) {
  int row = blockIdx.x;
  const float* xr = x + (size_t)row * H_;
  float vals[3];
  float s1 = 0.f, s2 = 0.f;
#pragma unroll
  for (int u = 0; u < 3; ++u) {
    float v = xr[threadIdx.x + 256 * u];
    vals[u] = v; s1 += v; s2 += v * v;
  }
  for (int o = 32; o > 0; o >>= 1) { s1 += __shfl_down(s1, o, 64); s2 += __shfl_down(s2, o, 64); }
  __shared__ float r1[4], r2[4];
  __shared__ float mu_s, rs_s;
  int w = threadIdx.x >> 6, lane = threadIdx.x & 63;
  if (lane == 0) { r1[w] = s1; r2[w] = s2; }
  __syncthreads();
  if (threadIdx.x == 0) {
    float t1 = r1[0] + r1[1] + r1[2] + r1[3];
    float t2 = r2[0] + r2[1] + r2[2] + r2[3];
    float mu = t1 / (float)H_;
    float var = t2 / (float)H_ - mu * mu;
    mu_s = mu; rs_s = rsqrtf(var + 1e-5f);
  }
  __syncthreads();
#pragma unroll
  for (int u = 0; u < 3; ++u) {
    int c = threadIdx.x + 256 * u;
    dst[(size_t)row * H_ + c] = (vals[u] - mu_s) * rs_s * g[c] + bb[c];
  }
}

}  // namespace

extern "C" void kernel_launch(void* const* d_in, const int* in_sizes, int n_in,
                              void* d_out, int out_size, void* d_ws, size_t ws_size,
                              hipStream_t stream) {
  (void)in_sizes; (void)n_in; (void)out_size; (void)ws_size;
  const float* hs = (const float*)d_in[0];
  const int* asp = (const int*)d_in[1];
  const int* osp = (const int*)d_in[2];
  const float* a_wih_f = (const float*)d_in[3];
  const float* a_whh_f = (const float*)d_in[4];
  const float* a_b_f   = (const float*)d_in[5];
  const float* a_wih_b = (const float*)d_in[6];
  const float* a_b_b   = (const float*)d_in[8];
  const float* o_wih_f = (const float*)d_in[9];
  const float* o_whh_f = (const float*)d_in[10];
  const float* o_b_f   = (const float*)d_in[11];
  const float* o_wih_b = (const float*)d_in[12];
  const float* o_b_b   = (const float*)d_in[14];
  const float* ao_in_w  = (const float*)d_in[15];
  const float* ao_in_b  = (const float*)d_in[16];
  const float* ao_out_w = (const float*)d_in[17];
  const float* ao_out_b = (const float*)d_in[18];
  const float* oa_in_w  = (const float*)d_in[19];
  const float* oa_in_b  = (const float*)d_in[20];
  const float* oa_out_w = (const float*)d_in[21];
  const float* oa_out_b = (const float*)d_in[22];
  const float* ln_a_g = (const float*)d_in[23];
  const float* ln_a_b = (const float*)d_in[24];
  const float* ln_o_g = (const float*)d_in[25];
  const float* ln_o_b = (const float*)d_in[26];
  const float* p_w1 = (const float*)d_in[27];
  const float* p_b1 = (const float*)d_in[28];
  const float* p_w2 = (const float*)d_in[29];
  const float* p_b2 = (const float*)d_in[30];
  float* out = (float*)d_out;

  char* ws = (char*)d_ws;
  unsigned short* WB = (unsigned short*)(ws + WB_B);
  unsigned short* xga = (unsigned short*)(ws + XGA_B);
  unsigned short* xgo = (unsigned short*)(ws + XGO_B);
  float* qkv = (float*)(ws + QKV_B);
  float* aot = (float*)(ws + AOT_B);
  float* rt  = (float*)(ws + RT_B);
  float* ea  = (float*)(ws + EA_B);
  float* eo  = (float*)(ws + EO_B);
  unsigned short* hb = (unsigned short*)(ws + HB_B);
  float* cst = (float*)(ws + CST_B);
  unsigned short* h1b = (unsigned short*)(ws + XGA_B); // overlay (xg dead after recurrence)
  int* I = (int*)(ws + INT_B);
  int* starts = I + I_STARTS;
  int* lens   = I + I_LENS;
  int* ord    = I + I_ORD;
  int* slens  = I + I_SLENS;
  int* xglist = I + I_XGLIST;
  int* toklist = I + I_TOKLIST;
  int* cnt    = I + I_CNT;

  // passthrough tokens
  hipMemcpyAsync(out, hs, (size_t)B_ * T_ * H_ * sizeof(float),
                 hipMemcpyDeviceToDevice, stream);
  hipMemsetAsync(ws + HB_B, 0, (CST_B - HB_B) + 2ull * 384 * 384 * 4, stream);  // h bufs + c

  // weight prep (f32 -> bf16; p_w1/p_w2 transposed)
  {
    PREP pp;
    pp.j[0]  = {a_wih_f,  WB + W_AWIF,  1536 * 768, 0, 0, 0};
    pp.j[1]  = {o_wih_f,  WB + W_OWIF,  1536 * 768, 0, 0, 0};
    pp.j[2]  = {a_wih_b,  WB + W_AWIB,  1536 * 768, 0, 0, 0};
    pp.j[3]  = {o_wih_b,  WB + W_OWIB,  1536 * 768, 0, 0, 0};
    pp.j[4]  = {a_whh_f,  WB + W_AWHH,  1536 * 384, 0, 0, 0};
    pp.j[5]  = {o_whh_f,  WB + W_OWHH,  1536 * 384, 0, 0, 0};
    pp.j[6]  = {ao_in_w,  WB + W_AOIN,  2 * 2304 * 768, 0, 0, 0};
    pp.j[7]  = {oa_in_w,  WB + W_OAIN,  2 * 2304 * 768, 0, 0, 0};
    pp.j[8]  = {ao_out_w, WB + W_AOOUT, 2 * 768 * 768, 0, 0, 0};
    pp.j[9]  = {oa_out_w, WB + W_OAOUT, 2 * 768 * 768, 0, 0, 0};
    pp.j[10] = {p_w1,     WB + W_PW1T,  1536 * 768, 1536, 768, 1};
    pp.j[11] = {p_w2,     WB + W_PW2T,  768 * 768,  768,  768, 1};
    prep_w<<<dim3(512, 12), 256, 0, stream>>>(pp);
  }

  // fused span metadata (scan-based, no global atomics)
  span_prep<<<1, 768, 0, stream>>>(asp, osp, starts, lens, ord, slens,
                                   xglist, toklist, cnt);

  // LSTM input projections -> xg bf16
  {
    GP g{}; g.A = hs; g.Wb = WB + W_AWIF; g.bias = a_b_f; g.Cb = xga;
    g.list = xglist; g.cnt = cnt; g.starts = starts; g.K = H_;
    mgemm<M_XG><<<dim3(48, 12), 256, 0, stream>>>(g);
  }
  {
    GP g{}; g.A = hs; g.Wb = WB + W_OWIF; g.bias = o_b_f; g.Cb = xgo;
    g.list = xglist + MAXTOK_; g.cnt = cnt + 1; g.starts = starts + NS_; g.K = H_;
    mgemm<M_XG><<<dim3(48, 12), 256, 0, stream>>>(g);
  }
  // backward LSTM: gate-gathered GEMM + fused activation (both types, one dispatch)
  {
    XBP x{};
    x.hs = hs; x.wa = WB + W_AWIB; x.wo = WB + W_OWIB;
    x.ba = a_b_b; x.bo = o_b_b; x.ea = ea; x.eo = eo;
    x.starts = starts; x.lens = lens;
    xgb_mfma<<<dim3(3, 12, 2), 256, 0, stream>>>(x);
  }

  // 16-step recurrence, h bf16 double-buffered in sorted order
  for (int t = 0; t < 16; ++t) {
    LP lp{};
    lp.hr = hb + (size_t)(t & 1) * 2 * 384 * 384;
    lp.hw = hb + (size_t)((t + 1) & 1) * 2 * 384 * 384;
    lp.c = cst;
    lp.xg_a = xga; lp.xg_o = xgo;
    lp.whh_a = WB + W_AWHH; lp.whh_o = WB + W_OWHH;
    lp.ord = ord; lp.slens = slens; lp.t = t;
    lstm_mfma<<<dim3(3, 12, 2), 256, 0, stream>>>(lp);
  }
  finalize_h<<<(2 * 384 * 384 + 255) / 256, 256, 0, stream>>>(hb, ord, ea, eo);

  // L=2 layers of cross attention
  for (int l = 0; l < 2; ++l) {
    for (int dir = 0; dir < 2; ++dir) {
      float* q  = dir ? eo : ea;
      float* kv = dir ? ea : eo;
      const unsigned short* inw = WB + (dir ? W_OAIN : W_AOIN) + (size_t)l * 2304 * 768;
      const float* inb = (dir ? oa_in_b : ao_in_b) + (size_t)l * 3 * H_;
      const unsigned short* ow = WB + (dir ? W_OAOUT : W_AOOUT) + (size_t)l * 768 * 768;
      const float* ob = (dir ? oa_out_b : ao_out_b) + (size_t)l * H_;
      const float* lg = (dir ? ln_o_g : ln_a_g) + (size_t)l * H_;
      const float* lb = (dir ? ln_o_b : ln_a_b) + (size_t)l * H_;
      {
        GP g{}; g.A = q; g.A2 = kv; g.Wb = inw; g.bias = inb; g.C = qkv; g.K = H_;
        mgemm<M_QKV><<<dim3(3, 18), 256, 0, stream>>>(g);
      }
      attn_core<<<128, 256, 0, stream>>>(qkv, aot);
      {
        GP g{}; g.A = aot; g.Wb = ow; g.bias = ob; g.resid = q; g.C = rt; g.K = H_;
        mgemm<M_OUTP><<<dim3(3, 6), 256, 0, stream>>>(g);
      }
      ln_k<<<NS_, 256, 0, stream>>>(rt, lg, lb, q);
    }
  }

  // apply spans: aspect pass then opinion pass
  for (int type = 0; type < 2; ++type) {
    {
      GP g{}; g.A = out; g.A2 = type ? eo : ea; g.Wb = WB + W_PW1T; g.bias = p_b1; g.Cb = h1b;
      g.list = toklist + (size_t)type * MAXTOK_; g.cnt = cnt + 2 + type; g.K = 2 * H_;
      mgemm<M_AP1><<<dim3(48, 6), 256, 0, stream>>>(g);
    }
    {
      GP g{}; g.Ab = h1b; g.Wb = WB + W_PW2T; g.bias = p_b2; g.C = out;
      g.list = toklist + (size_t)type * MAXTOK_; g.cnt = cnt + 2 + type; g.K = H_;
      mgemm<M_AP2><<<dim3(48, 6), 256, 0, stream>>>(g);
    }
  }
}